// Round 6
// baseline (239.965 us; speedup 1.0000x reference)
//
#include <hip/hip_runtime.h>

typedef __attribute__((ext_vector_type(8))) __bf16 bf16x8;
typedef __attribute__((ext_vector_type(4))) float f32x4;
typedef const __attribute__((address_space(1))) unsigned int gas_u32;
typedef __attribute__((address_space(3))) unsigned int las_u32;

__device__ __forceinline__ unsigned short f2bf(float f) {
  unsigned u = __builtin_bit_cast(unsigned, f);
  u = (u + 0x7FFFu + ((u >> 16) & 1u)) >> 16;
  return (unsigned short)u;
}
__device__ __forceinline__ float bf2f(unsigned short h) {
  return __builtin_bit_cast(float, (unsigned)h << 16);
}

// ---------- merged prep: f32->bf16 converts (+ sum-of-squares for the two weights) ----
// blocks [0,768): v | [768,864): q | [864,1344): v_w + ss0 | [1344,1536): q_w + ss1
__global__ __launch_bounds__(256) void k_prep(
    const float* __restrict__ v, const float* __restrict__ q,
    const float* __restrict__ vw, const float* __restrict__ qw,
    unsigned short* __restrict__ v_bf, unsigned short* __restrict__ q_bf,
    unsigned short* __restrict__ vw_bf, unsigned short* __restrict__ qw_bf,
    float* __restrict__ ss) {
  __shared__ float red[4];
  int bid = blockIdx.x, tid = threadIdx.x;
  const float* in;
  unsigned short* out;
  float* ssout = nullptr;
  int n8, b0, nb;
  if (bid < 768) {
    in = v; out = v_bf; n8 = 2097152; b0 = bid; nb = 768;
  } else if (bid < 864) {
    in = q; out = q_bf; n8 = 262144; b0 = bid - 768; nb = 96;
  } else if (bid < 1344) {
    in = vw; out = vw_bf; n8 = 786432; b0 = bid - 864; nb = 480; ssout = ss + 0;
  } else {
    in = qw; out = qw_bf; n8 = 393216; b0 = bid - 1344; nb = 192; ssout = ss + 1;
  }
  float s = 0.f;
  for (int i = b0 * 256 + tid; i < n8; i += nb * 256) {
    float4 a = ((const float4*)in)[2 * i];
    float4 b = ((const float4*)in)[2 * i + 1];
    if (ssout) {
      s += a.x * a.x + a.y * a.y + a.z * a.z + a.w * a.w;
      s += b.x * b.x + b.y * b.y + b.z * b.z + b.w * b.w;
    }
    uint4 o;
    o.x = f2bf(a.x) | ((unsigned)f2bf(a.y) << 16);
    o.y = f2bf(a.z) | ((unsigned)f2bf(a.w) << 16);
    o.z = f2bf(b.x) | ((unsigned)f2bf(b.y) << 16);
    o.w = f2bf(b.z) | ((unsigned)f2bf(b.w) << 16);
    ((uint4*)out)[i] = o;
  }
  if (ssout) {
    for (int off = 32; off; off >>= 1) s += __shfl_down(s, off);
    if ((tid & 63) == 0) red[tid >> 6] = s;
    __syncthreads();
    if (tid == 0) atomicAdd(ssout, red[0] + red[1] + red[2] + red[3]);
  }
}

// ======== GEMM1: 128x384 tile, 8 waves, read-ahead rotation + sched_barrier pinning ====
// bm-MAJOR (round-3 mapping, best measured). Pipeline as round-5 (fixed flights),
// but every ds-read cluster and stage cluster is PINNED with sched_barrier(0) so the
// compiler cannot sink reads to just-before-use (round-5 showed VGPR=104 -> it did).
__global__ __launch_bounds__(512, 2) void k_gemm_wn(
    const unsigned short* __restrict__ A, const unsigned short* __restrict__ B,
    const float* __restrict__ bias, const float* __restrict__ gptr,
    const float* __restrict__ ssptr, unsigned short* __restrict__ C,
    int M, int N, int K, int nbn) {
  __shared__ __align__(16) unsigned short lA[2 * 128 * 64];
  __shared__ __align__(16) unsigned short lB[2 * 384 * 64];
  const int tid = threadIdx.x;
  const int wid = tid >> 6, lane = tid & 63;
  const int l15 = lane & 15, l4 = lane >> 4;
  const int wm = wid >> 2, wn = wid & 3;  // 2M x 4N waves
  const int rr = tid >> 3;
  const int scol = ((tid & 7) ^ (rr & 7)) << 3;  // pre-swizzled source col (rule 21)

  int nwg = gridDim.x;
  int wg = (blockIdx.x & 7) * (nwg >> 3) + (blockIdx.x >> 3);
  int bm = wg / nbn, bn = wg % nbn;  // bm-major

  const unsigned short* Ab = A + (size_t)bm * 128 * K;
  const unsigned short* Bb = B + (size_t)bn * 384 * K;
  const int nt = K >> 6;

#define SB() __builtin_amdgcn_sched_barrier(0);

#define STAGEU(U, TS)                                                            \
  {                                                                              \
    int ts_ = (TS) < nt ? (TS) : nt - 1;                                         \
    if ((U) < 2) {                                                               \
      __builtin_amdgcn_global_load_lds(                                          \
          (gas_u32*)(Ab + (size_t)((U)*64 + rr) * K + ts_ * 64 + scol),          \
          (las_u32*)(lA + ((TS)&1) * 8192 + (U)*4096 + tid * 8), 16, 0, 0);      \
    } else {                                                                     \
      __builtin_amdgcn_global_load_lds(                                          \
          (gas_u32*)(Bb + (size_t)(((U)-2) * 64 + rr) * K + ts_ * 64 + scol),    \
          (las_u32*)(lB + ((TS)&1) * 24576 + ((U)-2) * 4096 + tid * 8), 16, 0,   \
          0);                                                                    \
    }                                                                            \
  }

#define LDSA(DST, MQ, TP)                                                        \
  _Pragma("unroll") for (int i2 = 0; i2 < 2; ++i2) {                             \
    int rl = wm * 64 + ((MQ)*2 + i2) * 16 + l15;                                 \
    const unsigned short* ap = lA + (TP)*8192 + rl * 64;                         \
    int s8 = rl & 7;                                                             \
    DST[i2][0] = *(const bf16x8*)(ap + ((l4 ^ s8) << 3));                        \
    DST[i2][1] = *(const bf16x8*)(ap + (((4 | l4) ^ s8) << 3));                  \
  }

#define LDSB(DST, NQ, TP)                                                        \
  _Pragma("unroll") for (int j3 = 0; j3 < 3; ++j3) {                             \
    int rl = wn * 96 + ((NQ)*3 + j3) * 16 + l15;                                 \
    const unsigned short* bp = lB + (TP)*24576 + rl * 64;                        \
    int s8 = rl & 7;                                                             \
    DST[j3][0] = *(const bf16x8*)(bp + ((l4 ^ s8) << 3));                        \
    DST[j3][1] = *(const bf16x8*)(bp + (((4 | l4) ^ s8) << 3));                  \
  }

#define MFMA12(MQ, NQ, AF, BF)                                                   \
  _Pragma("unroll") for (int ks = 0; ks < 2; ++ks)                               \
  _Pragma("unroll") for (int i2 = 0; i2 < 2; ++i2)                               \
  _Pragma("unroll") for (int j3 = 0; j3 < 3; ++j3)                               \
    acc[(MQ)*2 + i2][(NQ)*3 + j3] = __builtin_amdgcn_mfma_f32_16x16x32_bf16(     \
        AF[i2][ks], BF[j3][ks], acc[(MQ)*2 + i2][(NQ)*3 + j3], 0, 0, 0);

  f32x4 acc[4][6] = {};
  bf16x8 a0_[2][2], a1_[2][2], b0_[3][2], b1_[3][2];

  // ---- prologue ----
  STAGEU(0, 0) STAGEU(1, 0) STAGEU(2, 0) STAGEU(3, 0)
  STAGEU(4, 0) STAGEU(5, 0) STAGEU(6, 0) STAGEU(7, 0)
  STAGEU(0, 1) STAGEU(1, 1)
  asm volatile("s_waitcnt vmcnt(2)" ::: "memory");
  SB()
  __builtin_amdgcn_s_barrier();
  LDSA(a0_, 0, 0)
  SB()
  STAGEU(2, 1) STAGEU(3, 1) STAGEU(6, 1) STAGEU(7, 1)
  SB()
  LDSB(b0_, 0, 0)
  SB()

  for (int t = 0; t < nt; ++t) {
    const int cp = t & 1, np = (t + 1) & 1;
    // ---- ph0: read b1_(t); stage u45(t+1)->np; MFMA q00 ----
    LDSB(b1_, 1, cp)
    SB()
    STAGEU(4, t + 1) STAGEU(5, t + 1)
    SB()
    __builtin_amdgcn_s_setprio(1);
    MFMA12(0, 0, a0_, b0_)
    __builtin_amdgcn_s_setprio(0);
    // ---- ph1: read a1_(t); MFMA q01 ----
    LDSA(a1_, 1, cp)
    SB()
    __builtin_amdgcn_s_setprio(1);
    MFMA12(0, 1, a0_, b1_)
    __builtin_amdgcn_s_setprio(0);
    // ---- ph2: lgkm0 + vmcnt(6) + barrier; read a0_(t+1); stage u01(t+2); MFMA q10 ----
    asm volatile("s_waitcnt lgkmcnt(0)" ::: "memory");
    asm volatile("s_waitcnt vmcnt(6)" ::: "memory");
    SB()
    __builtin_amdgcn_s_barrier();
    LDSA(a0_, 0, np)
    SB()
    STAGEU(0, t + 2) STAGEU(1, t + 2)
    SB()
    __builtin_amdgcn_s_setprio(1);
    MFMA12(1, 0, a1_, b0_)
    __builtin_amdgcn_s_setprio(0);
    // ---- ph3: vmcnt(2) + barrier; read b0_(t+1); stage u23+u67(t+2); MFMA q11 ----
    asm volatile("s_waitcnt vmcnt(2)" ::: "memory");
    SB()
    __builtin_amdgcn_s_barrier();
    LDSB(b0_, 0, np)
    SB()
    STAGEU(2, t + 2) STAGEU(3, t + 2) STAGEU(6, t + 2) STAGEU(7, t + 2)
    SB()
    __builtin_amdgcn_s_setprio(1);
    MFMA12(1, 1, a1_, b1_)
    __builtin_amdgcn_s_setprio(0);
  }

  asm volatile("s_waitcnt vmcnt(0)" ::: "memory");

  float s = gptr[0] / sqrtf(ssptr[0]);
#pragma unroll
  for (int nj = 0; nj < 6; ++nj) {
    int gcol = bn * 384 + wn * 96 + nj * 16 + l15;
    float bv = bias[gcol];
#pragma unroll
    for (int mi = 0; mi < 4; ++mi) {
#pragma unroll
      for (int r = 0; r < 4; ++r) {
        int grow = bm * 128 + wm * 64 + mi * 16 + l4 * 4 + r;
        float v = fmaxf(acc[mi][nj][r] * s + bv, 0.f);
        C[(size_t)grow * N + gcol] = f2bf(v);
      }
    }
  }
#undef STAGEU
#undef LDSA
#undef LDSB
#undef MFMA12
#undef SB
}

// ---------------- bf16 GEMM (m97 structure) for the small GEMM ----------------
__global__ __launch_bounds__(256, 2) void k_gemm_bt(
    const unsigned short* __restrict__ A, const unsigned short* __restrict__ B,
    const float* __restrict__ bias, const float* __restrict__ gptr,
    const float* __restrict__ ssptr, unsigned short* __restrict__ C,
    int M, int N, int K, int nbm) {
  __shared__ __align__(16) unsigned short lA[128 * 64];
  __shared__ __align__(16) unsigned short lB[128 * 64];
  int tid = threadIdx.x;
  int wid = tid >> 6, lane = tid & 63;
  int l15 = lane & 15, l4 = lane >> 4;
  int w0 = wid >> 1, w1 = wid & 1;

  int nwg = gridDim.x;
  int wg = (blockIdx.x & 7) * (nwg >> 3) + (blockIdx.x >> 3);
  int bm = wg % nbm, bn = wg / nbm;

  const unsigned short* Ab = A + (size_t)bm * 128 * K;
  const unsigned short* Bb = B + (size_t)bn * 128 * K;

  f32x4 acc[4][4] = {};

  for (int k0 = 0; k0 < K; k0 += 64) {
    __syncthreads();
#pragma unroll
    for (int i = 0; i < 4; ++i) {
      int ebase = (i * 4 + wid) << 9;
      int eoff = ebase + lane * 8;
      int row = eoff >> 6, col = eoff & 63;
      __builtin_amdgcn_global_load_lds(
          (gas_u32*)(Ab + (size_t)row * K + k0 + col),
          (las_u32*)(lA + ebase), 16, 0, 0);
      __builtin_amdgcn_global_load_lds(
          (gas_u32*)(Bb + (size_t)row * K + k0 + col),
          (las_u32*)(lB + ebase), 16, 0, 0);
    }
    __syncthreads();
#pragma unroll
    for (int ks = 0; ks < 2; ++ks) {
      bf16x8 af[4], bfr[4];
#pragma unroll
      for (int mi = 0; mi < 4; ++mi)
        af[mi] = *(const bf16x8*)(lA + ((w0 * 64 + mi * 16 + l15) * 64 + ks * 32 + l4 * 8));
#pragma unroll
      for (int nj = 0; nj < 4; ++nj)
        bfr[nj] = *(const bf16x8*)(lB + ((w1 * 64 + nj * 16 + l15) * 64 + ks * 32 + l4 * 8));
#pragma unroll
      for (int mi = 0; mi < 4; ++mi)
#pragma unroll
        for (int nj = 0; nj < 4; ++nj)
          acc[mi][nj] =
              __builtin_amdgcn_mfma_f32_16x16x32_bf16(af[mi], bfr[nj], acc[mi][nj], 0, 0, 0);
    }
  }

  float s = gptr[0] / sqrtf(ssptr[0]);
#pragma unroll
  for (int mi = 0; mi < 4; ++mi)
#pragma unroll
    for (int nj = 0; nj < 4; ++nj) {
      int col = bn * 128 + w1 * 64 + nj * 16 + l15;
      float bv = bias[col];
#pragma unroll
      for (int r = 0; r < 4; ++r) {
        int row = bm * 128 + w0 * 64 + mi * 16 + l4 * 4 + r;
        float v = fmaxf(acc[mi][nj][r] * s + bv, 0.f);
        C[(size_t)row * N + col] = f2bf(v);
      }
    }
}

// -------- glimpse v4: h-QUAD (4 heads/block, 128 blocks) pipelined --------
// out[b,h,v,q] = sum_k hm[h,k]*v_[b,v,k]*q_[b,q,k] + hb[h]; block id = h4*64 + b,
// heads h4*4..h4*4+3. V[b] read once per 4 heads: LLC traffic ~130MB (was ~250).
// Depth-2 pipeline: V triple-buffer (DMA), Q+hm reg double-buffer, lQ double-buffer.
// vmcnt queue sim (issue order per iter: QLOAD then VSTAGE):
//   prologue: [Q0(9) Q1(9) V0(4) V1(4)]=26 -> vmcnt(17) drains Q0.
//   iter T: +QLOAD(T+2)(9)=26 -> vmcnt(13) drains V(T)+Q(T+1) exactly. Steady.
__global__ __launch_bounds__(256, 2) void k_glimpse4(
    const unsigned short* __restrict__ Vh, const unsigned short* __restrict__ Qh,
    const float* __restrict__ hmat, const float* __restrict__ hbias,
    float* __restrict__ out) {
  __shared__ __align__(16) unsigned short lV[3][128 * 64];     // 48 KB
  __shared__ __align__(16) unsigned short lQ[2][4][32 * 64];   // 32 KB
  int tid = threadIdx.x;
  int wid = tid >> 6, lane = tid & 63;
  int l15 = lane & 15, l4 = lane >> 4;

  int id = blockIdx.x;
  int b = id & 63, h4 = id >> 6;  // heads h4*4 .. h4*4+3

  const unsigned short* Vb = Vh + (size_t)b * 128 * 3072;
  const unsigned short* Qb = Qh + (size_t)b * 32 * 3072;
  const float* hr0 = hmat + (h4 * 4 + 0) * 3072;
  const float* hr1 = hmat + (h4 * 4 + 1) * 3072;
  const float* hr2 = hmat + (h4 * 4 + 2) * 3072;
  const float* hr3 = hmat + (h4 * 4 + 3) * 3072;

  f32x4 acc[4][2][2] = {};
  int eoff = tid * 8;
  int qr = eoff >> 6, qc = eoff & 63;
  const int NT = 48;

#define VSTAGE(T, SLOT)                                                          \
  {                                                                              \
    int tc = (T) < NT ? (T) : NT - 1;                                            \
    _Pragma("unroll") for (int i = 0; i < 4; ++i) {                              \
      int ebase = (i * 4 + wid) << 9;                                            \
      int eo = ebase + lane * 8;                                                 \
      int row = eo >> 6, col = eo & 63;                                          \
      __builtin_amdgcn_global_load_lds(                                          \
          (gas_u32*)(Vb + (size_t)row * 3072 + tc * 64 + col),                   \
          (las_u32*)(&lV[SLOT][0] + ebase), 16, 0, 0);                           \
    }                                                                            \
  }

  // QLOAD: 1 uint4 + 8 float4 = 9 vmem loads
#define QLOAD(T, RQ, H)                                                          \
  {                                                                              \
    int tc = (T) < NT ? (T) : NT - 1;                                            \
    RQ = *(const uint4*)(Qb + (size_t)qr * 3072 + tc * 64 + qc);                 \
    H[0] = ((const float4*)(hr0 + tc * 64 + qc))[0];                             \
    H[1] = ((const float4*)(hr0 + tc * 64 + qc))[1];                             \
    H[2] = ((const float4*)(hr1 + tc * 64 + qc))[0];                             \
    H[3] = ((const float4*)(hr1 + tc * 64 + qc))[1];                             \
    H[4] = ((const float4*)(hr2 + tc * 64 + qc))[0];                             \
    H[5] = ((const float4*)(hr2 + tc * 64 + qc))[1];                             \
    H[6] = ((const float4*)(hr3 + tc * 64 + qc))[0];                             \
    H[7] = ((const float4*)(hr3 + tc * 64 + qc))[1];                             \
  }

#define QWRITE(CB, RQ, H)                                                        \
  {                                                                              \
    float e0 = bf2f((unsigned short)(RQ.x & 0xffff));                            \
    float e1 = bf2f((unsigned short)(RQ.x >> 16));                               \
    float e2 = bf2f((unsigned short)(RQ.y & 0xffff));                            \
    float e3 = bf2f((unsigned short)(RQ.y >> 16));                               \
    float e4 = bf2f((unsigned short)(RQ.z & 0xffff));                            \
    float e5 = bf2f((unsigned short)(RQ.z >> 16));                               \
    float e6 = bf2f((unsigned short)(RQ.w & 0xffff));                            \
    float e7 = bf2f((unsigned short)(RQ.w >> 16));                               \
    _Pragma("unroll") for (int hh = 0; hh < 4; ++hh) {                           \
      uint4 o;                                                                   \
      o.x = f2bf(e0 * H[hh * 2].x) | ((unsigned)f2bf(e1 * H[hh * 2].y) << 16);   \
      o.y = f2bf(e2 * H[hh * 2].z) | ((unsigned)f2bf(e3 * H[hh * 2].w) << 16);   \
      o.z = f2bf(e4 * H[hh * 2 + 1].x) |                                         \
            ((unsigned)f2bf(e5 * H[hh * 2 + 1].y) << 16);                        \
      o.w = f2bf(e6 * H[hh * 2 + 1].z) |                                         \
            ((unsigned)f2bf(e7 * H[hh * 2 + 1].w) << 16);                        \
      *(uint4*)(&lQ[CB][hh][0] + eoff) = o;                                      \
    }                                                                            \
  }

#define GMFMA(SLOT, CB)                                                          \
  _Pragma("unroll") for (int ks = 0; ks < 2; ++ks) {                             \
    bf16x8 af[2];                                                                \
    _Pragma("unroll") for (int mi = 0; mi < 2; ++mi)                             \
      af[mi] = *(const bf16x8*)(&lV[SLOT][0] +                                   \
                                ((wid * 32 + mi * 16 + l15) * 64 + ks * 32 + l4 * 8)); \
    _Pragma("unroll") for (int hh = 0; hh < 4; ++hh) {                           \
      bf16x8 bq[2];                                                              \
      _Pragma("unroll") for (int nj = 0; nj < 2; ++nj)                           \
        bq[nj] = *(const bf16x8*)(&lQ[CB][hh][0] +                               \
                                  ((nj * 16 + l15) * 64 + ks * 32 + l4 * 8));    \
      _Pragma("unroll") for (int mi = 0; mi < 2; ++mi)                           \
        _Pragma("unroll") for (int nj = 0; nj < 2; ++nj)                         \
          acc[hh][mi][nj] = __builtin_amdgcn_mfma_f32_16x16x32_bf16(             \
              af[mi], bq[nj], acc[hh][mi][nj], 0, 0, 0);                         \
    }                                                                            \
  }

#define GBODY(T, CQ, CH, NQ, NH)                                                 \
  {                                                                              \
    QLOAD((T) + 2, NQ, NH)                                                       \
    asm volatile("s_waitcnt vmcnt(13)" ::: "memory");                            \
    asm volatile("s_waitcnt lgkmcnt(0)" ::: "memory");                           \
    __builtin_amdgcn_sched_barrier(0);                                           \
    __builtin_amdgcn_s_barrier();                                                \
    VSTAGE((T) + 2, ((T) + 2) % 3)                                               \
    QWRITE(((T) + 1) & 1, CQ, CH)                                                \
    GMFMA((T) % 3, (T) & 1)                                                      \
  }

  uint4 aq, bq_;
  float4 ah[8], bh[8];

  // ---- prologue ----
  QLOAD(0, aq, ah)
  QLOAD(1, bq_, bh)
  VSTAGE(0, 0)
  VSTAGE(1, 1)
  asm volatile("s_waitcnt vmcnt(17)" ::: "memory");
  __builtin_amdgcn_sched_barrier(0);
  QWRITE(0, aq, ah)

  for (int t = 0; t < NT; t += 2) {
    GBODY(t, bq_, bh, aq, ah)
    GBODY(t + 1, aq, ah, bq_, bh)
  }
  asm volatile("s_waitcnt vmcnt(0) lgkmcnt(0)" ::: "memory");

#pragma unroll
  for (int hh = 0; hh < 4; ++hh) {
    int h = h4 * 4 + hh;
    float hb = hbias[h];
    float* ob = out + (size_t)(b * 8 + h) * 128 * 32;
#pragma unroll
    for (int mi = 0; mi < 2; ++mi)
#pragma unroll
      for (int nj = 0; nj < 2; ++nj)
#pragma unroll
        for (int r = 0; r < 4; ++r) {
          int row = wid * 32 + mi * 16 + l4 * 4 + r;
          int col = nj * 16 + l15;
          ob[row * 32 + col] = acc[hh][mi][nj][r] + hb;
        }
  }
#undef VSTAGE
#undef QLOAD
#undef QWRITE
#undef GMFMA
#undef GBODY
}

extern "C" void kernel_launch(void* const* d_in, const int* in_sizes, int n_in,
                              void* d_out, int out_size, void* d_ws, size_t ws_size,
                              hipStream_t stream) {
  const float* v = (const float*)d_in[0];
  const float* q = (const float*)d_in[1];
  const float* v_w = (const float*)d_in[2];
  const float* v_g = (const float*)d_in[3];
  const float* v_b = (const float*)d_in[4];
  const float* q_w = (const float*)d_in[5];
  const float* q_g = (const float*)d_in[6];
  const float* q_b = (const float*)d_in[7];
  const float* hmat = (const float*)d_in[8];
  const float* hbias = (const float*)d_in[9];
  float* out = (float*)d_out;

  const size_t n_v = 16777216;   // 64*128*2048
  const size_t n_vw = 6291456;   // 3072*2048
  const size_t n_q = 2097152;    // 64*32*1024
  const size_t n_qw = 3145728;   // 3072*1024
  const size_t n_vh = 25165824;  // 8192*3072
  const size_t n_qh = 6291456;   // 2048*3072

  char* ws = (char*)d_ws;
  float* ss = (float*)ws;
  size_t off = 256;
  unsigned short* v_bf = (unsigned short*)(ws + off);  off += n_v * 2;
  unsigned short* vw_bf = (unsigned short*)(ws + off); off += n_vw * 2;
  unsigned short* q_bf = (unsigned short*)(ws + off);  off += n_q * 2;
  unsigned short* qw_bf = (unsigned short*)(ws + off); off += n_qw * 2;
  unsigned short* v_h = (unsigned short*)(ws + off);   off += n_vh * 2;
  unsigned short* q_h = (unsigned short*)(ws + off);   off += n_qh * 2;

  (void)hipMemsetAsync(ss, 0, 8, stream);
  k_prep<<<1536, 256, 0, stream>>>(v, q, v_w, q_w, v_bf, q_bf, vw_bf, qw_bf, ss);

  // GEMM1: 8192x3072x2048, 128x384 tiles -> 64 bm x 8 bn = 512 blocks (bm-major)
  k_gemm_wn<<<512, 512, 0, stream>>>(v_bf, vw_bf, v_b, v_g, ss + 0, v_h,
                                     8192, 3072, 2048, 8);
  // GEMM2: 2048x3072x1024, 128^2 tiles -> 16 bm x 24 bn = 384 blocks
  k_gemm_bt<<<384, 256, 0, stream>>>(q_bf, qw_bf, q_b, q_g, ss + 1, q_h,
                                     2048, 3072, 1024, 16);

  k_glimpse4<<<128, 256, 0, stream>>>(v_h, q_h, hmat, hbias, out);
}

// Round 7
// 219.295 us; speedup vs baseline: 1.0943x; 1.0943x over previous
//
#include <hip/hip_runtime.h>

typedef __attribute__((ext_vector_type(8))) __bf16 bf16x8;
typedef __attribute__((ext_vector_type(4))) float f32x4;
typedef const __attribute__((address_space(1))) unsigned int gas_u32;
typedef __attribute__((address_space(3))) unsigned int las_u32;

__device__ __forceinline__ unsigned short f2bf(float f) {
  unsigned u = __builtin_bit_cast(unsigned, f);
  u = (u + 0x7FFFu + ((u >> 16) & 1u)) >> 16;
  return (unsigned short)u;
}
__device__ __forceinline__ float bf2f(unsigned short h) {
  return __builtin_bit_cast(float, (unsigned)h << 16);
}

// ---------- merged prep: f32->bf16 converts (+ sum-of-squares for the two weights) ----
__global__ __launch_bounds__(256) void k_prep(
    const float* __restrict__ v, const float* __restrict__ q,
    const float* __restrict__ vw, const float* __restrict__ qw,
    unsigned short* __restrict__ v_bf, unsigned short* __restrict__ q_bf,
    unsigned short* __restrict__ vw_bf, unsigned short* __restrict__ qw_bf,
    float* __restrict__ ss) {
  __shared__ float red[4];
  int bid = blockIdx.x, tid = threadIdx.x;
  const float* in;
  unsigned short* out;
  float* ssout = nullptr;
  int n8, b0, nb;
  if (bid < 768) {
    in = v; out = v_bf; n8 = 2097152; b0 = bid; nb = 768;
  } else if (bid < 864) {
    in = q; out = q_bf; n8 = 262144; b0 = bid - 768; nb = 96;
  } else if (bid < 1344) {
    in = vw; out = vw_bf; n8 = 786432; b0 = bid - 864; nb = 480; ssout = ss + 0;
  } else {
    in = qw; out = qw_bf; n8 = 393216; b0 = bid - 1344; nb = 192; ssout = ss + 1;
  }
  float s = 0.f;
  for (int i = b0 * 256 + tid; i < n8; i += nb * 256) {
    float4 a = ((const float4*)in)[2 * i];
    float4 b = ((const float4*)in)[2 * i + 1];
    if (ssout) {
      s += a.x * a.x + a.y * a.y + a.z * a.z + a.w * a.w;
      s += b.x * b.x + b.y * b.y + b.z * b.z + b.w * b.w;
    }
    uint4 o;
    o.x = f2bf(a.x) | ((unsigned)f2bf(a.y) << 16);
    o.y = f2bf(a.z) | ((unsigned)f2bf(a.w) << 16);
    o.z = f2bf(b.x) | ((unsigned)f2bf(b.y) << 16);
    o.w = f2bf(b.z) | ((unsigned)f2bf(b.w) << 16);
    ((uint4*)out)[i] = o;
  }
  if (ssout) {
    for (int off = 32; off; off >>= 1) s += __shfl_down(s, off);
    if ((tid & 63) == 0) red[tid >> 6] = s;
    __syncthreads();
    if (tid == 0) atomicAdd(ssout, red[0] + red[1] + red[2] + red[3]);
  }
}

// ======== GEMM1: 128x192 tile, 4 waves, rotation, 2 BLOCKS/CU (80KB LDS) ========
// Two independent barrier domains per CU: when one block stalls at its barrier/
// vmcnt, the other block's waves feed the MFMA pipe (m114 cross-block overlap).
// Wave grid 2Mx2N, wave tile 64x96, acc[4][6] (AGPR). BK=64 double-buffered.
// Stage units (8KB, 2 loads/thread): A0,A1 (rows 0-63/64-127), B0,B1,B2 (64 cols each).
// Per tile: ph0 stages B2(t+1)->np; ph2 stages A0,A1(t+2)->cb; ph3 stages B0,B1(t+2)->cb.
// Queue-simulated waits: ph2 vmcnt(6) [drains A(t+1); leaves B01+B2(t+1)=6];
//                        ph3 vmcnt(4) [drains all B(t+1); leaves A(t+2)=4].
// Flights: A 4ph, B01 4ph, B2 3ph. Tail clamps source tile (idempotent).
__global__ __launch_bounds__(256, 2) void k_gemm_wn(
    const unsigned short* __restrict__ A, const unsigned short* __restrict__ B,
    const float* __restrict__ bias, const float* __restrict__ gptr,
    const float* __restrict__ ssptr, unsigned short* __restrict__ C,
    int M, int N, int K, int nbn) {
  __shared__ __align__(16) unsigned short lA[2 * 128 * 64];  // 32 KB
  __shared__ __align__(16) unsigned short lB[2 * 192 * 64];  // 48 KB
  const int tid = threadIdx.x;
  const int wid = tid >> 6, lane = tid & 63;
  const int l15 = lane & 15, l4 = lane >> 4;
  const int wm = wid >> 1, wn = wid & 1;  // 2M x 2N waves
  const int rr8 = tid >> 3;               // row within 32-row half-unit
  const int scol8 = (((tid & 7)) ^ (rr8 & 7)) << 3;  // pre-swizzled source col

  int nwg = gridDim.x;
  int wg = (blockIdx.x & 7) * (nwg >> 3) + (blockIdx.x >> 3);
  int bm = wg / nbn, bn = wg % nbn;  // bm-major (measured best)

  const unsigned short* Ab = A + (size_t)bm * 128 * K;
  const unsigned short* Bb = B + (size_t)bn * 192 * K;
  const int nt = K >> 6;

#define SB() __builtin_amdgcn_sched_barrier(0);

#define STAGE_A(U, TS)                                                             \
  {                                                                                \
    int ts_ = (TS) < nt ? (TS) : nt - 1;                                           \
    _Pragma("unroll") for (int j = 0; j < 2; ++j) {                                \
      __builtin_amdgcn_global_load_lds(                                            \
          (gas_u32*)(Ab + (size_t)((U)*64 + j * 32 + rr8) * K + ts_ * 64 + scol8), \
          (las_u32*)(lA + ((TS)&1) * 8192 + (U)*4096 + j * 2048 + tid * 8), 16, 0, \
          0);                                                                      \
    }                                                                              \
  }

#define STAGE_B(U, TS)                                                             \
  {                                                                                \
    int ts_ = (TS) < nt ? (TS) : nt - 1;                                           \
    _Pragma("unroll") for (int j = 0; j < 2; ++j) {                                \
      __builtin_amdgcn_global_load_lds(                                            \
          (gas_u32*)(Bb + (size_t)((U)*64 + j * 32 + rr8) * K + ts_ * 64 + scol8), \
          (las_u32*)(lB + ((TS)&1) * 12288 + (U)*4096 + j * 2048 + tid * 8), 16,   \
          0, 0);                                                                   \
    }                                                                              \
  }

#define LDSA(DST, MQ, TP)                                                          \
  _Pragma("unroll") for (int i2 = 0; i2 < 2; ++i2) {                               \
    int rl = wm * 64 + ((MQ)*2 + i2) * 16 + l15;                                   \
    const unsigned short* ap = lA + (TP)*8192 + rl * 64;                           \
    int s8 = rl & 7;                                                               \
    DST[i2][0] = *(const bf16x8*)(ap + ((l4 ^ s8) << 3));                          \
    DST[i2][1] = *(const bf16x8*)(ap + (((4 | l4) ^ s8) << 3));                    \
  }

#define LDSB(DST, NQ, TP)                                                          \
  _Pragma("unroll") for (int j3 = 0; j3 < 3; ++j3) {                               \
    int rl = wn * 96 + ((NQ)*3 + j3) * 16 + l15;                                   \
    const unsigned short* bp = lB + (TP)*12288 + rl * 64;                          \
    int s8 = rl & 7;                                                               \
    DST[j3][0] = *(const bf16x8*)(bp + ((l4 ^ s8) << 3));                          \
    DST[j3][1] = *(const bf16x8*)(bp + (((4 | l4) ^ s8) << 3));                    \
  }

#define MFMA12(MQ, NQ, AF, BF)                                                     \
  _Pragma("unroll") for (int ks = 0; ks < 2; ++ks)                                 \
  _Pragma("unroll") for (int i2 = 0; i2 < 2; ++i2)                                 \
  _Pragma("unroll") for (int j3 = 0; j3 < 3; ++j3)                                 \
    acc[(MQ)*2 + i2][(NQ)*3 + j3] = __builtin_amdgcn_mfma_f32_16x16x32_bf16(       \
        AF[i2][ks], BF[j3][ks], acc[(MQ)*2 + i2][(NQ)*3 + j3], 0, 0, 0);

  f32x4 acc[4][6] = {};
  bf16x8 a0_[2][2], a1_[2][2], b0_[3][2], b1_[3][2];

  // ---- prologue: tile0 (10 loads) + A(1) (4); wait tile0; B01(1) post-barrier ----
  STAGE_A(0, 0) STAGE_A(1, 0) STAGE_B(0, 0) STAGE_B(1, 0) STAGE_B(2, 0)
  STAGE_A(0, 1) STAGE_A(1, 1)
  asm volatile("s_waitcnt vmcnt(4)" ::: "memory");
  SB()
  __builtin_amdgcn_s_barrier();
  LDSA(a0_, 0, 0)
  STAGE_B(0, 1) STAGE_B(1, 1)
  LDSB(b0_, 0, 0)

  for (int t = 0; t < nt; ++t) {
    const int cp = t & 1, np = (t + 1) & 1;
    // ---- ph0: read b1_(t); stage B2(t+1)->np; MFMA q00 ----
    LDSB(b1_, 1, cp)
    STAGE_B(2, t + 1)
    __builtin_amdgcn_s_setprio(1);
    MFMA12(0, 0, a0_, b0_)
    __builtin_amdgcn_s_setprio(0);
    // ---- ph1: read a1_(t); MFMA q01 ----
    LDSA(a1_, 1, cp)
    __builtin_amdgcn_s_setprio(1);
    MFMA12(0, 1, a0_, b1_)
    __builtin_amdgcn_s_setprio(0);
    // ---- ph2: lgkm0 + vmcnt(6) + barrier; read a0_(t+1); stage A(t+2)->cb; MFMA q10 --
    asm volatile("s_waitcnt lgkmcnt(0)" ::: "memory");
    asm volatile("s_waitcnt vmcnt(6)" ::: "memory");
    SB()
    __builtin_amdgcn_s_barrier();
    LDSA(a0_, 0, np)
    STAGE_A(0, t + 2) STAGE_A(1, t + 2)
    __builtin_amdgcn_s_setprio(1);
    MFMA12(1, 0, a1_, b0_)
    __builtin_amdgcn_s_setprio(0);
    // ---- ph3: vmcnt(4) + barrier; read b0_(t+1); stage B01(t+2)->cb; MFMA q11 ----
    asm volatile("s_waitcnt vmcnt(4)" ::: "memory");
    SB()
    __builtin_amdgcn_s_barrier();
    LDSB(b0_, 0, np)
    STAGE_B(0, t + 2) STAGE_B(1, t + 2)
    __builtin_amdgcn_s_setprio(1);
    MFMA12(1, 1, a1_, b1_)
    __builtin_amdgcn_s_setprio(0);
  }

  asm volatile("s_waitcnt vmcnt(0)" ::: "memory");

  float s = gptr[0] / sqrtf(ssptr[0]);
#pragma unroll
  for (int nj = 0; nj < 6; ++nj) {
    int gcol = bn * 192 + wn * 96 + nj * 16 + l15;
    float bv = bias[gcol];
#pragma unroll
    for (int mi = 0; mi < 4; ++mi) {
#pragma unroll
      for (int r = 0; r < 4; ++r) {
        int grow = bm * 128 + wm * 64 + mi * 16 + l4 * 4 + r;
        float v = fmaxf(acc[mi][nj][r] * s + bv, 0.f);
        C[(size_t)grow * N + gcol] = f2bf(v);
      }
    }
  }
#undef STAGE_A
#undef STAGE_B
#undef LDSA
#undef LDSB
#undef MFMA12
#undef SB
}

// ---------------- bf16 GEMM (m97 structure) for the small GEMM ----------------
__global__ __launch_bounds__(256, 2) void k_gemm_bt(
    const unsigned short* __restrict__ A, const unsigned short* __restrict__ B,
    const float* __restrict__ bias, const float* __restrict__ gptr,
    const float* __restrict__ ssptr, unsigned short* __restrict__ C,
    int M, int N, int K, int nbm) {
  __shared__ __align__(16) unsigned short lA[128 * 64];
  __shared__ __align__(16) unsigned short lB[128 * 64];
  int tid = threadIdx.x;
  int wid = tid >> 6, lane = tid & 63;
  int l15 = lane & 15, l4 = lane >> 4;
  int w0 = wid >> 1, w1 = wid & 1;

  int nwg = gridDim.x;
  int wg = (blockIdx.x & 7) * (nwg >> 3) + (blockIdx.x >> 3);
  int bm = wg % nbm, bn = wg / nbm;

  const unsigned short* Ab = A + (size_t)bm * 128 * K;
  const unsigned short* Bb = B + (size_t)bn * 128 * K;

  f32x4 acc[4][4] = {};

  for (int k0 = 0; k0 < K; k0 += 64) {
    __syncthreads();
#pragma unroll
    for (int i = 0; i < 4; ++i) {
      int ebase = (i * 4 + wid) << 9;
      int eoff = ebase + lane * 8;
      int row = eoff >> 6, col = eoff & 63;
      __builtin_amdgcn_global_load_lds(
          (gas_u32*)(Ab + (size_t)row * K + k0 + col),
          (las_u32*)(lA + ebase), 16, 0, 0);
      __builtin_amdgcn_global_load_lds(
          (gas_u32*)(Bb + (size_t)row * K + k0 + col),
          (las_u32*)(lB + ebase), 16, 0, 0);
    }
    __syncthreads();
#pragma unroll
    for (int ks = 0; ks < 2; ++ks) {
      bf16x8 af[4], bfr[4];
#pragma unroll
      for (int mi = 0; mi < 4; ++mi)
        af[mi] = *(const bf16x8*)(lA + ((w0 * 64 + mi * 16 + l15) * 64 + ks * 32 + l4 * 8));
#pragma unroll
      for (int nj = 0; nj < 4; ++nj)
        bfr[nj] = *(const bf16x8*)(lB + ((w1 * 64 + nj * 16 + l15) * 64 + ks * 32 + l4 * 8));
#pragma unroll
      for (int mi = 0; mi < 4; ++mi)
#pragma unroll
        for (int nj = 0; nj < 4; ++nj)
          acc[mi][nj] =
              __builtin_amdgcn_mfma_f32_16x16x32_bf16(af[mi], bfr[nj], acc[mi][nj], 0, 0, 0);
    }
  }

  float s = gptr[0] / sqrtf(ssptr[0]);
#pragma unroll
  for (int mi = 0; mi < 4; ++mi)
#pragma unroll
    for (int nj = 0; nj < 4; ++nj) {
      int col = bn * 128 + w1 * 64 + nj * 16 + l15;
      float bv = bias[col];
#pragma unroll
      for (int r = 0; r < 4; ++r) {
        int row = bm * 128 + w0 * 64 + mi * 16 + l4 * 4 + r;
        float v = fmaxf(acc[mi][nj][r] * s + bv, 0.f);
        C[(size_t)row * N + col] = f2bf(v);
      }
    }
}

// -------- glimpse v5: 256 blocks (V-half split), XOR-swizzled LDS, h-quad --------
// block id = hv*64 + b; hv = {h4 (head pair-group) , vh (V half)}: vh = hv>>1, h4 = hv&1.
// Each block: 64 V-rows x 4 heads. Swizzle kills the 16-way conflicts on frag reads.
// vmcnt sim: per iter QLOAD(9 instr) + VSTAGE(2): wait leaves V(t+1)2+Q(t+2)9 = 11.
// Prologue: 22 outstanding -> vmcnt(13) drains Q(0).
__global__ __launch_bounds__(256, 2) void k_glimpse5(
    const unsigned short* __restrict__ Vh, const unsigned short* __restrict__ Qh,
    const float* __restrict__ hmat, const float* __restrict__ hbias,
    float* __restrict__ out) {
  __shared__ __align__(16) unsigned short lV[3][64 * 64];    // 24 KB
  __shared__ __align__(16) unsigned short lQ[2][4][32 * 64]; // 32 KB
  int tid = threadIdx.x;
  int wid = tid >> 6, lane = tid & 63;
  int l15 = lane & 15, l4 = lane >> 4;

  int id = blockIdx.x;
  int b = id & 63, hv = id >> 6;
  int h4 = hv & 1, vh = hv >> 1;  // heads h4*4..+3, V rows vh*64..+63

  const unsigned short* Vb = Vh + (size_t)b * 128 * 3072 + (size_t)vh * 64 * 3072;
  const unsigned short* Qb = Qh + (size_t)b * 32 * 3072;
  const float* hr0 = hmat + (h4 * 4 + 0) * 3072;
  const float* hr1 = hmat + (h4 * 4 + 1) * 3072;
  const float* hr2 = hmat + (h4 * 4 + 2) * 3072;
  const float* hr3 = hmat + (h4 * 4 + 3) * 3072;

  f32x4 acc[4][2] = {};
  const int rr8 = tid >> 3;
  const int ch8 = tid & 7;
  const int scol8 = (ch8 ^ (rr8 & 7)) << 3;       // pre-swizzled V source col
  const int qwoff = rr8 * 64 + scol8;              // swizzled lQ write offset (row rr8)
  const int qc = ch8 * 8;                          // plain Q/hm source col
  const int NT = 48;

#define VSTAGE(T, SLOT)                                                          \
  {                                                                              \
    int tc = (T) < NT ? (T) : NT - 1;                                            \
    _Pragma("unroll") for (int j = 0; j < 2; ++j) {                              \
      __builtin_amdgcn_global_load_lds(                                          \
          (gas_u32*)(Vb + (size_t)(j * 32 + rr8) * 3072 + tc * 64 + scol8),      \
          (las_u32*)(&lV[SLOT][0] + j * 2048 + tid * 8), 16, 0, 0);              \
    }                                                                            \
  }

#define QLOAD(T, RQ, H)                                                          \
  {                                                                              \
    int tc = (T) < NT ? (T) : NT - 1;                                            \
    RQ = *(const uint4*)(Qb + (size_t)rr8 * 3072 + tc * 64 + qc);                \
    H[0] = ((const float4*)(hr0 + tc * 64 + qc))[0];                             \
    H[1] = ((const float4*)(hr0 + tc * 64 + qc))[1];                             \
    H[2] = ((const float4*)(hr1 + tc * 64 + qc))[0];                             \
    H[3] = ((const float4*)(hr1 + tc * 64 + qc))[1];                             \
    H[4] = ((const float4*)(hr2 + tc * 64 + qc))[0];                             \
    H[5] = ((const float4*)(hr2 + tc * 64 + qc))[1];                             \
    H[6] = ((const float4*)(hr3 + tc * 64 + qc))[0];                             \
    H[7] = ((const float4*)(hr3 + tc * 64 + qc))[1];                             \
  }

#define QWRITE(CB, RQ, H)                                                        \
  {                                                                              \
    float e0 = bf2f((unsigned short)(RQ.x & 0xffff));                            \
    float e1 = bf2f((unsigned short)(RQ.x >> 16));                               \
    float e2 = bf2f((unsigned short)(RQ.y & 0xffff));                            \
    float e3 = bf2f((unsigned short)(RQ.y >> 16));                               \
    float e4 = bf2f((unsigned short)(RQ.z & 0xffff));                            \
    float e5 = bf2f((unsigned short)(RQ.z >> 16));                               \
    float e6 = bf2f((unsigned short)(RQ.w & 0xffff));                            \
    float e7 = bf2f((unsigned short)(RQ.w >> 16));                               \
    _Pragma("unroll") for (int hh = 0; hh < 4; ++hh) {                           \
      uint4 o;                                                                   \
      o.x = f2bf(e0 * H[hh * 2].x) | ((unsigned)f2bf(e1 * H[hh * 2].y) << 16);   \
      o.y = f2bf(e2 * H[hh * 2].z) | ((unsigned)f2bf(e3 * H[hh * 2].w) << 16);   \
      o.z = f2bf(e4 * H[hh * 2 + 1].x) |                                         \
            ((unsigned)f2bf(e5 * H[hh * 2 + 1].y) << 16);                        \
      o.w = f2bf(e6 * H[hh * 2 + 1].z) |                                         \
            ((unsigned)f2bf(e7 * H[hh * 2 + 1].w) << 16);                        \
      *(uint4*)(&lQ[CB][hh][0] + qwoff) = o;                                     \
    }                                                                            \
  }

#define GMFMA(SLOT, CB)                                                          \
  {                                                                              \
    int rlv = wid * 16 + l15;                                                    \
    int s8v = rlv & 7;                                                           \
    bf16x8 af[2];                                                                \
    af[0] = *(const bf16x8*)(&lV[SLOT][0] + rlv * 64 + ((l4 ^ s8v) << 3));       \
    af[1] = *(const bf16x8*)(&lV[SLOT][0] + rlv * 64 + (((4 | l4) ^ s8v) << 3)); \
    _Pragma("unroll") for (int hh = 0; hh < 4; ++hh) {                           \
      _Pragma("unroll") for (int nj = 0; nj < 2; ++nj) {                         \
        int rlq = nj * 16 + l15;                                                 \
        int s8q = rlq & 7;                                                       \
        bf16x8 bq0 = *(const bf16x8*)(&lQ[CB][hh][0] + rlq * 64 +                \
                                      ((l4 ^ s8q) << 3));                        \
        bf16x8 bq1 = *(const bf16x8*)(&lQ[CB][hh][0] + rlq * 64 +                \
                                      (((4 | l4) ^ s8q) << 3));                  \
        acc[hh][nj] =                                                            \
            __builtin_amdgcn_mfma_f32_16x16x32_bf16(af[0], bq0, acc[hh][nj], 0, 0, 0); \
        acc[hh][nj] =                                                            \
            __builtin_amdgcn_mfma_f32_16x16x32_bf16(af[1], bq1, acc[hh][nj], 0, 0, 0); \
      }                                                                          \
    }                                                                            \
  }

#define GBODY(T, CQ, CH, NQ, NH)                                                 \
  {                                                                              \
    QLOAD((T) + 2, NQ, NH)                                                       \
    asm volatile("s_waitcnt vmcnt(11)" ::: "memory");                            \
    asm volatile("s_waitcnt lgkmcnt(0)" ::: "memory");                           \
    __builtin_amdgcn_sched_barrier(0);                                           \
    __builtin_amdgcn_s_barrier();                                                \
    VSTAGE((T) + 2, ((T) + 2) % 3)                                               \
    QWRITE(((T) + 1) & 1, CQ, CH)                                                \
    GMFMA((T) % 3, (T) & 1)                                                      \
  }

  uint4 aq, bq_;
  float4 ah[8], bh[8];

  QLOAD(0, aq, ah)
  QLOAD(1, bq_, bh)
  VSTAGE(0, 0)
  VSTAGE(1, 1)
  asm volatile("s_waitcnt vmcnt(13)" ::: "memory");
  __builtin_amdgcn_sched_barrier(0);
  QWRITE(0, aq, ah)

  for (int t = 0; t < NT; t += 2) {
    GBODY(t, bq_, bh, aq, ah)
    GBODY(t + 1, aq, ah, bq_, bh)
  }
  asm volatile("s_waitcnt vmcnt(0) lgkmcnt(0)" ::: "memory");

#pragma unroll
  for (int hh = 0; hh < 4; ++hh) {
    int h = h4 * 4 + hh;
    float hb = hbias[h];
    float* ob = out + (size_t)(b * 8 + h) * 128 * 32;
#pragma unroll
    for (int nj = 0; nj < 2; ++nj)
#pragma unroll
      for (int r = 0; r < 4; ++r) {
        int row = vh * 64 + wid * 16 + l4 * 4 + r;
        int col = nj * 16 + l15;
        ob[row * 32 + col] = acc[hh][nj][r] + hb;
      }
  }
#undef VSTAGE
#undef QLOAD
#undef QWRITE
#undef GMFMA
#undef GBODY
}

extern "C" void kernel_launch(void* const* d_in, const int* in_sizes, int n_in,
                              void* d_out, int out_size, void* d_ws, size_t ws_size,
                              hipStream_t stream) {
  const float* v = (const float*)d_in[0];
  const float* q = (const float*)d_in[1];
  const float* v_w = (const float*)d_in[2];
  const float* v_g = (const float*)d_in[3];
  const float* v_b = (const float*)d_in[4];
  const float* q_w = (const float*)d_in[5];
  const float* q_g = (const float*)d_in[6];
  const float* q_b = (const float*)d_in[7];
  const float* hmat = (const float*)d_in[8];
  const float* hbias = (const float*)d_in[9];
  float* out = (float*)d_out;

  const size_t n_v = 16777216;   // 64*128*2048
  const size_t n_vw = 6291456;   // 3072*2048
  const size_t n_q = 2097152;    // 64*32*1024
  const size_t n_qw = 3145728;   // 3072*1024
  const size_t n_vh = 25165824;  // 8192*3072
  const size_t n_qh = 6291456;   // 2048*3072

  char* ws = (char*)d_ws;
  float* ss = (float*)ws;
  size_t off = 256;
  unsigned short* v_bf = (unsigned short*)(ws + off);  off += n_v * 2;
  unsigned short* vw_bf = (unsigned short*)(ws + off); off += n_vw * 2;
  unsigned short* q_bf = (unsigned short*)(ws + off);  off += n_q * 2;
  unsigned short* qw_bf = (unsigned short*)(ws + off); off += n_qw * 2;
  unsigned short* v_h = (unsigned short*)(ws + off);   off += n_vh * 2;
  unsigned short* q_h = (unsigned short*)(ws + off);   off += n_qh * 2;

  (void)hipMemsetAsync(ss, 0, 8, stream);
  k_prep<<<1536, 256, 0, stream>>>(v, q, v_w, q_w, v_bf, q_bf, vw_bf, qw_bf, ss);

  // GEMM1: 8192x3072x2048, 128x192 tiles -> 64 bm x 16 bn = 1024 blocks (2/CU resident)
  k_gemm_wn<<<1024, 256, 0, stream>>>(v_bf, vw_bf, v_b, v_g, ss + 0, v_h,
                                      8192, 3072, 2048, 16);
  // GEMM2: 2048x3072x1024, 128^2 tiles -> 16 bm x 24 bn = 384 blocks
  k_gemm_bt<<<384, 256, 0, stream>>>(q_bf, qw_bf, q_b, q_g, ss + 1, q_h,
                                     2048, 3072, 1024, 16);

  k_glimpse5<<<256, 256, 0, stream>>>(v_h, q_h, hmat, hbias, out);
}

// Round 8
// 207.984 us; speedup vs baseline: 1.1538x; 1.0544x over previous
//
#include <hip/hip_runtime.h>

typedef __attribute__((ext_vector_type(8))) __bf16 bf16x8;
typedef __attribute__((ext_vector_type(4))) float f32x4;
typedef const __attribute__((address_space(1))) unsigned int gas_u32;
typedef __attribute__((address_space(3))) unsigned int las_u32;

__device__ __forceinline__ unsigned short f2bf(float f) {
  unsigned u = __builtin_bit_cast(unsigned, f);
  u = (u + 0x7FFFu + ((u >> 16) & 1u)) >> 16;
  return (unsigned short)u;
}
__device__ __forceinline__ float bf2f(unsigned short h) {
  return __builtin_bit_cast(float, (unsigned)h << 16);
}

// ---------- merged prep: f32->bf16 converts (+ sum-of-squares for the two weights) ----
__global__ __launch_bounds__(256) void k_prep(
    const float* __restrict__ v, const float* __restrict__ q,
    const float* __restrict__ vw, const float* __restrict__ qw,
    unsigned short* __restrict__ v_bf, unsigned short* __restrict__ q_bf,
    unsigned short* __restrict__ vw_bf, unsigned short* __restrict__ qw_bf,
    float* __restrict__ ss) {
  __shared__ float red[4];
  int bid = blockIdx.x, tid = threadIdx.x;
  const float* in;
  unsigned short* out;
  float* ssout = nullptr;
  int n8, b0, nb;
  if (bid < 768) {
    in = v; out = v_bf; n8 = 2097152; b0 = bid; nb = 768;
  } else if (bid < 864) {
    in = q; out = q_bf; n8 = 262144; b0 = bid - 768; nb = 96;
  } else if (bid < 1344) {
    in = vw; out = vw_bf; n8 = 786432; b0 = bid - 864; nb = 480; ssout = ss + 0;
  } else {
    in = qw; out = qw_bf; n8 = 393216; b0 = bid - 1344; nb = 192; ssout = ss + 1;
  }
  float s = 0.f;
  for (int i = b0 * 256 + tid; i < n8; i += nb * 256) {
    float4 a = ((const float4*)in)[2 * i];
    float4 b = ((const float4*)in)[2 * i + 1];
    if (ssout) {
      s += a.x * a.x + a.y * a.y + a.z * a.z + a.w * a.w;
      s += b.x * b.x + b.y * b.y + b.z * b.z + b.w * b.w;
    }
    uint4 o;
    o.x = f2bf(a.x) | ((unsigned)f2bf(a.y) << 16);
    o.y = f2bf(a.z) | ((unsigned)f2bf(a.w) << 16);
    o.z = f2bf(b.x) | ((unsigned)f2bf(b.y) << 16);
    o.w = f2bf(b.z) | ((unsigned)f2bf(b.w) << 16);
    ((uint4*)out)[i] = o;
  }
  if (ssout) {
    for (int off = 32; off; off >>= 1) s += __shfl_down(s, off);
    if ((tid & 63) == 0) red[tid >> 6] = s;
    __syncthreads();
    if (tid == 0) atomicAdd(ssout, red[0] + red[1] + red[2] + red[3]);
  }
}

// ======== merged GEMM: 128x192 tile, 4 waves, rotation, 2 blocks/CU, unroll-2 ========
// blocks [0,1024) = GEMM1 (8192x3072x2048, 64bm x 16bn); [1024,1280) = GEMM2
// (2048x3072x1024, 16bm x 16bn). Per-segment bijective XCD swizzle.
// K-loop unrolled x2 so buffer indices are literals (ds addressing folds to offset:
// immediates) and staging sources are hoisted per-lane pointers + uniform ts*64 add —
// cuts the ~24% VALUBusy of R7 (addressing was stealing issue slots from MFMA).
// Schedule identical to R7 (queue-sim verified): per tile ph0 stages B2(t+1)->np,
// ph2 [lgkm0+vmcnt(6)+bar] stages A(t+2)->cp, ph3 [vmcnt(4)+bar] stages B01(t+2)->cp.
__global__ __launch_bounds__(256, 2) void k_gemm_cmb(
    const unsigned short* __restrict__ A1, const unsigned short* __restrict__ B1,
    const float* __restrict__ bias1, const float* __restrict__ g1,
    const float* __restrict__ ss1, unsigned short* __restrict__ C1,
    const unsigned short* __restrict__ A2, const unsigned short* __restrict__ B2,
    const float* __restrict__ bias2, const float* __restrict__ g2,
    const float* __restrict__ ss2, unsigned short* __restrict__ C2) {
  __shared__ __align__(16) unsigned short lA[2 * 128 * 64];  // 32 KB
  __shared__ __align__(16) unsigned short lB[2 * 192 * 64];  // 48 KB
  const int tid = threadIdx.x;
  const int wid = tid >> 6, lane = tid & 63;
  const int l15 = lane & 15, l4 = lane >> 4;
  const int wm = wid >> 1, wn = wid & 1;  // 2M x 2N waves
  const int rr8 = tid >> 3;
  const int scol8 = ((tid & 7) ^ (rr8 & 7)) << 3;  // pre-swizzled source col (rule 21)

  const unsigned short* A;
  const unsigned short* B;
  const float* bias;
  const float* gptr;
  const float* ssptr;
  unsigned short* C;
  int K, nt, wg;
  if (blockIdx.x < 1024) {
    int bid = blockIdx.x;
    wg = (bid & 7) * 128 + (bid >> 3);
    A = A1; B = B1; bias = bias1; gptr = g1; ssptr = ss1; C = C1;
    K = 2048; nt = 32;
  } else {
    int bid = blockIdx.x - 1024;
    wg = (bid & 7) * 32 + (bid >> 3);
    A = A2; B = B2; bias = bias2; gptr = g2; ssptr = ss2; C = C2;
    K = 1024; nt = 16;
  }
  const int bm = wg >> 4, bn = wg & 15;  // bm-major, nbn = 16

  const unsigned short* Ab = A + (size_t)bm * 128 * K;
  const unsigned short* Bb = B + (size_t)bn * 192 * K;

  // hoisted per-lane staging source pointers (unit U, half j)
  const unsigned short* sA00 = Ab + (size_t)(rr8) * K + scol8;
  const unsigned short* sA01 = Ab + (size_t)(32 + rr8) * K + scol8;
  const unsigned short* sA10 = Ab + (size_t)(64 + rr8) * K + scol8;
  const unsigned short* sA11 = Ab + (size_t)(96 + rr8) * K + scol8;
  const unsigned short* sB00 = Bb + (size_t)(rr8) * K + scol8;
  const unsigned short* sB01 = Bb + (size_t)(32 + rr8) * K + scol8;
  const unsigned short* sB10 = Bb + (size_t)(64 + rr8) * K + scol8;
  const unsigned short* sB11 = Bb + (size_t)(96 + rr8) * K + scol8;
  const unsigned short* sB20 = Bb + (size_t)(128 + rr8) * K + scol8;
  const unsigned short* sB21 = Bb + (size_t)(160 + rr8) * K + scol8;

#define SB() __builtin_amdgcn_sched_barrier(0);

#define STAGE_A(U, TS, BUFI)                                                       \
  {                                                                                \
    int ts_ = (TS) < nt ? (TS) : nt - 1;                                           \
    __builtin_amdgcn_global_load_lds(                                              \
        (gas_u32*)(sA##U##0 + (size_t)ts_ * 64),                                   \
        (las_u32*)(lA + (BUFI)*8192 + (U)*4096 + tid * 8), 16, 0, 0);              \
    __builtin_amdgcn_global_load_lds(                                              \
        (gas_u32*)(sA##U##1 + (size_t)ts_ * 64),                                   \
        (las_u32*)(lA + (BUFI)*8192 + (U)*4096 + 2048 + tid * 8), 16, 0, 0);       \
  }

#define STAGE_B(U, TS, BUFI)                                                       \
  {                                                                                \
    int ts_ = (TS) < nt ? (TS) : nt - 1;                                           \
    __builtin_amdgcn_global_load_lds(                                              \
        (gas_u32*)(sB##U##0 + (size_t)ts_ * 64),                                   \
        (las_u32*)(lB + (BUFI)*12288 + (U)*4096 + tid * 8), 16, 0, 0);             \
    __builtin_amdgcn_global_load_lds(                                              \
        (gas_u32*)(sB##U##1 + (size_t)ts_ * 64),                                   \
        (las_u32*)(lB + (BUFI)*12288 + (U)*4096 + 2048 + tid * 8), 16, 0, 0);      \
  }

#define LDSA(DST, MQ, TP)                                                          \
  _Pragma("unroll") for (int i2 = 0; i2 < 2; ++i2) {                               \
    int rl = wm * 64 + ((MQ)*2 + i2) * 16 + l15;                                   \
    const unsigned short* ap = lA + (TP)*8192 + rl * 64;                           \
    int s8 = rl & 7;                                                               \
    DST[i2][0] = *(const bf16x8*)(ap + ((l4 ^ s8) << 3));                          \
    DST[i2][1] = *(const bf16x8*)(ap + (((4 | l4) ^ s8) << 3));                    \
  }

#define LDSB(DST, NQ, TP)                                                          \
  _Pragma("unroll") for (int j3 = 0; j3 < 3; ++j3) {                               \
    int rl = wn * 96 + ((NQ)*3 + j3) * 16 + l15;                                   \
    const unsigned short* bp = lB + (TP)*12288 + rl * 64;                          \
    int s8 = rl & 7;                                                               \
    DST[j3][0] = *(const bf16x8*)(bp + ((l4 ^ s8) << 3));                          \
    DST[j3][1] = *(const bf16x8*)(bp + (((4 | l4) ^ s8) << 3));                    \
  }

#define MFMA12(MQ, NQ, AF, BF)                                                     \
  _Pragma("unroll") for (int ks = 0; ks < 2; ++ks)                                 \
  _Pragma("unroll") for (int i2 = 0; i2 < 2; ++i2)                                 \
  _Pragma("unroll") for (int j3 = 0; j3 < 3; ++j3)                                 \
    acc[(MQ)*2 + i2][(NQ)*3 + j3] = __builtin_amdgcn_mfma_f32_16x16x32_bf16(       \
        AF[i2][ks], BF[j3][ks], acc[(MQ)*2 + i2][(NQ)*3 + j3], 0, 0, 0);

// one K-tile, all indices literal: CP = buffer of tile t, NP = other buffer
#define TILE_BODY(T, CP, NP)                                                       \
  LDSB(b1_, 1, CP)                                                                 \
  STAGE_B(2, (T) + 1, NP)                                                          \
  __builtin_amdgcn_s_setprio(1);                                                   \
  MFMA12(0, 0, a0_, b0_)                                                           \
  __builtin_amdgcn_s_setprio(0);                                                   \
  LDSA(a1_, 1, CP)                                                                 \
  __builtin_amdgcn_s_setprio(1);                                                   \
  MFMA12(0, 1, a0_, b1_)                                                           \
  __builtin_amdgcn_s_setprio(0);                                                   \
  asm volatile("s_waitcnt lgkmcnt(0)" ::: "memory");                               \
  asm volatile("s_waitcnt vmcnt(6)" ::: "memory");                                 \
  SB()                                                                             \
  __builtin_amdgcn_s_barrier();                                                    \
  LDSA(a0_, 0, NP)                                                                 \
  STAGE_A(0, (T) + 2, CP) STAGE_A(1, (T) + 2, CP)                                  \
  __builtin_amdgcn_s_setprio(1);                                                   \
  MFMA12(1, 0, a1_, b0_)                                                           \
  __builtin_amdgcn_s_setprio(0);                                                   \
  asm volatile("s_waitcnt vmcnt(4)" ::: "memory");                                 \
  SB()                                                                             \
  __builtin_amdgcn_s_barrier();                                                    \
  LDSB(b0_, 0, NP)                                                                 \
  STAGE_B(0, (T) + 2, CP) STAGE_B(1, (T) + 2, CP)                                  \
  __builtin_amdgcn_s_setprio(1);                                                   \
  MFMA12(1, 1, a1_, b1_)                                                           \
  __builtin_amdgcn_s_setprio(0);

  f32x4 acc[4][6] = {};
  bf16x8 a0_[2][2], a1_[2][2], b0_[3][2], b1_[3][2];

  // ---- prologue: tile0 (10 loads) + A(1) (4); wait tile0; B01(1) post-barrier ----
  STAGE_A(0, 0, 0) STAGE_A(1, 0, 0) STAGE_B(0, 0, 0) STAGE_B(1, 0, 0) STAGE_B(2, 0, 0)
  STAGE_A(0, 1, 1) STAGE_A(1, 1, 1)
  asm volatile("s_waitcnt vmcnt(4)" ::: "memory");
  SB()
  __builtin_amdgcn_s_barrier();
  LDSA(a0_, 0, 0)
  STAGE_B(0, 1, 1) STAGE_B(1, 1, 1)
  LDSB(b0_, 0, 0)

  for (int t = 0; t < nt; t += 2) {
    TILE_BODY(t, 0, 1)      // even tile: cp=0, np=1
    TILE_BODY(t + 1, 1, 0)  // odd tile:  cp=1, np=0
  }

  asm volatile("s_waitcnt vmcnt(0)" ::: "memory");

  const int N = 3072;
  float s = gptr[0] / sqrtf(ssptr[0]);
#pragma unroll
  for (int nj = 0; nj < 6; ++nj) {
    int gcol = bn * 192 + wn * 96 + nj * 16 + l15;
    float bv = bias[gcol];
#pragma unroll
    for (int mi = 0; mi < 4; ++mi) {
#pragma unroll
      for (int r = 0; r < 4; ++r) {
        int grow = bm * 128 + wm * 64 + mi * 16 + l4 * 4 + r;
        float v = fmaxf(acc[mi][nj][r] * s + bv, 0.f);
        C[(size_t)grow * N + gcol] = f2bf(v);
      }
    }
  }
#undef STAGE_A
#undef STAGE_B
#undef LDSA
#undef LDSB
#undef MFMA12
#undef TILE_BODY
#undef SB
}

// -------- glimpse v5b: b-MAJOR block ids (4 blocks sharing V[b] -> same XCD L2) --------
// block id = b*4 + hv; hv = {h4, vh}. 64 V-rows x 4 heads per block, XOR-swizzled LDS.
__global__ __launch_bounds__(256, 2) void k_glimpse5(
    const unsigned short* __restrict__ Vh, const unsigned short* __restrict__ Qh,
    const float* __restrict__ hmat, const float* __restrict__ hbias,
    float* __restrict__ out) {
  __shared__ __align__(16) unsigned short lV[3][64 * 64];    // 24 KB
  __shared__ __align__(16) unsigned short lQ[2][4][32 * 64]; // 32 KB
  int tid = threadIdx.x;
  int wid = tid >> 6, lane = tid & 63;
  int l15 = lane & 15, l4 = lane >> 4;

  int id = blockIdx.x;
  int b = id >> 2, hv = id & 3;
  int h4 = hv & 1, vh = hv >> 1;  // heads h4*4..+3, V rows vh*64..+63

  const unsigned short* Vb = Vh + (size_t)b * 128 * 3072 + (size_t)vh * 64 * 3072;
  const unsigned short* Qb = Qh + (size_t)b * 32 * 3072;
  const float* hr0 = hmat + (h4 * 4 + 0) * 3072;
  const float* hr1 = hmat + (h4 * 4 + 1) * 3072;
  const float* hr2 = hmat + (h4 * 4 + 2) * 3072;
  const float* hr3 = hmat + (h4 * 4 + 3) * 3072;

  f32x4 acc[4][2] = {};
  const int rr8 = tid >> 3;
  const int ch8 = tid & 7;
  const int scol8 = (ch8 ^ (rr8 & 7)) << 3;
  const int qwoff = rr8 * 64 + scol8;
  const int qc = ch8 * 8;
  const int NT = 48;

#define VSTAGE(T, SLOT)                                                          \
  {                                                                              \
    int tc = (T) < NT ? (T) : NT - 1;                                            \
    _Pragma("unroll") for (int j = 0; j < 2; ++j) {                              \
      __builtin_amdgcn_global_load_lds(                                          \
          (gas_u32*)(Vb + (size_t)(j * 32 + rr8) * 3072 + tc * 64 + scol8),      \
          (las_u32*)(&lV[SLOT][0] + j * 2048 + tid * 8), 16, 0, 0);              \
    }                                                                            \
  }

#define QLOAD(T, RQ, H)                                                          \
  {                                                                              \
    int tc = (T) < NT ? (T) : NT - 1;                                            \
    RQ = *(const uint4*)(Qb + (size_t)rr8 * 3072 + tc * 64 + qc);                \
    H[0] = ((const float4*)(hr0 + tc * 64 + qc))[0];                             \
    H[1] = ((const float4*)(hr0 + tc * 64 + qc))[1];                             \
    H[2] = ((const float4*)(hr1 + tc * 64 + qc))[0];                             \
    H[3] = ((const float4*)(hr1 + tc * 64 + qc))[1];                             \
    H[4] = ((const float4*)(hr2 + tc * 64 + qc))[0];                             \
    H[5] = ((const float4*)(hr2 + tc * 64 + qc))[1];                             \
    H[6] = ((const float4*)(hr3 + tc * 64 + qc))[0];                             \
    H[7] = ((const float4*)(hr3 + tc * 64 + qc))[1];                             \
  }

#define QWRITE(CB, RQ, H)                                                        \
  {                                                                              \
    float e0 = bf2f((unsigned short)(RQ.x & 0xffff));                            \
    float e1 = bf2f((unsigned short)(RQ.x >> 16));                               \
    float e2 = bf2f((unsigned short)(RQ.y & 0xffff));                            \
    float e3 = bf2f((unsigned short)(RQ.y >> 16));                               \
    float e4 = bf2f((unsigned short)(RQ.z & 0xffff));                            \
    float e5 = bf2f((unsigned short)(RQ.z >> 16));                               \
    float e6 = bf2f((unsigned short)(RQ.w & 0xffff));                            \
    float e7 = bf2f((unsigned short)(RQ.w >> 16));                               \
    _Pragma("unroll") for (int hh = 0; hh < 4; ++hh) {                           \
      uint4 o;                                                                   \
      o.x = f2bf(e0 * H[hh * 2].x) | ((unsigned)f2bf(e1 * H[hh * 2].y) << 16);   \
      o.y = f2bf(e2 * H[hh * 2].z) | ((unsigned)f2bf(e3 * H[hh * 2].w) << 16);   \
      o.z = f2bf(e4 * H[hh * 2 + 1].x) |                                         \
            ((unsigned)f2bf(e5 * H[hh * 2 + 1].y) << 16);                        \
      o.w = f2bf(e6 * H[hh * 2 + 1].z) |                                         \
            ((unsigned)f2bf(e7 * H[hh * 2 + 1].w) << 16);                        \
      *(uint4*)(&lQ[CB][hh][0] + qwoff) = o;                                     \
    }                                                                            \
  }

#define GMFMA(SLOT, CB)                                                          \
  {                                                                              \
    int rlv = wid * 16 + l15;                                                    \
    int s8v = rlv & 7;                                                           \
    bf16x8 af[2];                                                                \
    af[0] = *(const bf16x8*)(&lV[SLOT][0] + rlv * 64 + ((l4 ^ s8v) << 3));       \
    af[1] = *(const bf16x8*)(&lV[SLOT][0] + rlv * 64 + (((4 | l4) ^ s8v) << 3)); \
    _Pragma("unroll") for (int hh = 0; hh < 4; ++hh) {                           \
      _Pragma("unroll") for (int nj = 0; nj < 2; ++nj) {                         \
        int rlq = nj * 16 + l15;                                                 \
        int s8q = rlq & 7;                                                       \
        bf16x8 bq0 = *(const bf16x8*)(&lQ[CB][hh][0] + rlq * 64 +                \
                                      ((l4 ^ s8q) << 3));                        \
        bf16x8 bq1 = *(const bf16x8*)(&lQ[CB][hh][0] + rlq * 64 +                \
                                      (((4 | l4) ^ s8q) << 3));                  \
        acc[hh][nj] =                                                            \
            __builtin_amdgcn_mfma_f32_16x16x32_bf16(af[0], bq0, acc[hh][nj], 0, 0, 0); \
        acc[hh][nj] =                                                            \
            __builtin_amdgcn_mfma_f32_16x16x32_bf16(af[1], bq1, acc[hh][nj], 0, 0, 0); \
      }                                                                          \
    }                                                                            \
  }

#define GBODY(T, CQ, CH, NQ, NH)                                                 \
  {                                                                              \
    QLOAD((T) + 2, NQ, NH)                                                       \
    asm volatile("s_waitcnt vmcnt(11)" ::: "memory");                            \
    asm volatile("s_waitcnt lgkmcnt(0)" ::: "memory");                           \
    __builtin_amdgcn_sched_barrier(0);                                           \
    __builtin_amdgcn_s_barrier();                                                \
    VSTAGE((T) + 2, ((T) + 2) % 3)                                               \
    QWRITE(((T) + 1) & 1, CQ, CH)                                                \
    GMFMA((T) % 3, (T) & 1)                                                      \
  }

  uint4 aq, bq_;
  float4 ah[8], bh[8];

  QLOAD(0, aq, ah)
  QLOAD(1, bq_, bh)
  VSTAGE(0, 0)
  VSTAGE(1, 1)
  asm volatile("s_waitcnt vmcnt(13)" ::: "memory");
  __builtin_amdgcn_sched_barrier(0);
  QWRITE(0, aq, ah)

  for (int t = 0; t < NT; t += 2) {
    GBODY(t, bq_, bh, aq, ah)
    GBODY(t + 1, aq, ah, bq_, bh)
  }
  asm volatile("s_waitcnt vmcnt(0) lgkmcnt(0)" ::: "memory");

#pragma unroll
  for (int hh = 0; hh < 4; ++hh) {
    int h = h4 * 4 + hh;
    float hb = hbias[h];
    float* ob = out + (size_t)(b * 8 + h) * 128 * 32;
#pragma unroll
    for (int nj = 0; nj < 2; ++nj)
#pragma unroll
      for (int r = 0; r < 4; ++r) {
        int row = vh * 64 + wid * 16 + l4 * 4 + r;
        int col = nj * 16 + l15;
        ob[row * 32 + col] = acc[hh][nj][r] + hb;
      }
  }
#undef VSTAGE
#undef QLOAD
#undef QWRITE
#undef GMFMA
#undef GBODY
}

extern "C" void kernel_launch(void* const* d_in, const int* in_sizes, int n_in,
                              void* d_out, int out_size, void* d_ws, size_t ws_size,
                              hipStream_t stream) {
  const float* v = (const float*)d_in[0];
  const float* q = (const float*)d_in[1];
  const float* v_w = (const float*)d_in[2];
  const float* v_g = (const float*)d_in[3];
  const float* v_b = (const float*)d_in[4];
  const float* q_w = (const float*)d_in[5];
  const float* q_g = (const float*)d_in[6];
  const float* q_b = (const float*)d_in[7];
  const float* hmat = (const float*)d_in[8];
  const float* hbias = (const float*)d_in[9];
  float* out = (float*)d_out;

  const size_t n_v = 16777216;   // 64*128*2048
  const size_t n_vw = 6291456;   // 3072*2048
  const size_t n_q = 2097152;    // 64*32*1024
  const size_t n_qw = 3145728;   // 3072*1024
  const size_t n_vh = 25165824;  // 8192*3072
  const size_t n_qh = 6291456;   // 2048*3072

  char* ws = (char*)d_ws;
  float* ss = (float*)ws;
  size_t off = 256;
  unsigned short* v_bf = (unsigned short*)(ws + off);  off += n_v * 2;
  unsigned short* vw_bf = (unsigned short*)(ws + off); off += n_vw * 2;
  unsigned short* q_bf = (unsigned short*)(ws + off);  off += n_q * 2;
  unsigned short* qw_bf = (unsigned short*)(ws + off); off += n_qw * 2;
  unsigned short* v_h = (unsigned short*)(ws + off);   off += n_vh * 2;
  unsigned short* q_h = (unsigned short*)(ws + off);   off += n_qh * 2;

  (void)hipMemsetAsync(ss, 0, 8, stream);
  k_prep<<<1536, 256, 0, stream>>>(v, q, v_w, q_w, v_bf, q_bf, vw_bf, qw_bf, ss);

  // merged GEMM1 (1024 blocks) + GEMM2 (256 blocks)
  k_gemm_cmb<<<1280, 256, 0, stream>>>(v_bf, vw_bf, v_b, v_g, ss + 0, v_h,
                                       q_bf, qw_bf, q_b, q_g, ss + 1, q_h);

  k_glimpse5<<<256, 256, 0, stream>>>(v_h, q_h, hmat, hbias, out);
}

// Round 9
// 207.313 us; speedup vs baseline: 1.1575x; 1.0032x over previous
//
#include <hip/hip_runtime.h>

typedef __attribute__((ext_vector_type(8))) __bf16 bf16x8;
typedef __attribute__((ext_vector_type(4))) float f32x4;
typedef const __attribute__((address_space(1))) unsigned int gas_u32;
typedef __attribute__((address_space(3))) unsigned int las_u32;

__device__ __forceinline__ unsigned short f2bf(float f) {
  unsigned u = __builtin_bit_cast(unsigned, f);
  u = (u + 0x7FFFu + ((u >> 16) & 1u)) >> 16;
  return (unsigned short)u;
}
__device__ __forceinline__ float bf2f(unsigned short h) {
  return __builtin_bit_cast(float, (unsigned)h << 16);
}

// ---------- merged prep: f32->bf16 converts (+ sum-of-squares for the two weights) ----
// blocks rebalanced to traffic: v 896 | q 112 | vw 352 | qw 176
__global__ __launch_bounds__(256) void k_prep(
    const float* __restrict__ v, const float* __restrict__ q,
    const float* __restrict__ vw, const float* __restrict__ qw,
    unsigned short* __restrict__ v_bf, unsigned short* __restrict__ q_bf,
    unsigned short* __restrict__ vw_bf, unsigned short* __restrict__ qw_bf,
    float* __restrict__ ss) {
  __shared__ float red[4];
  int bid = blockIdx.x, tid = threadIdx.x;
  const float* in;
  unsigned short* out;
  float* ssout = nullptr;
  int n8, b0, nb;
  if (bid < 896) {
    in = v; out = v_bf; n8 = 2097152; b0 = bid; nb = 896;
  } else if (bid < 1008) {
    in = q; out = q_bf; n8 = 262144; b0 = bid - 896; nb = 112;
  } else if (bid < 1360) {
    in = vw; out = vw_bf; n8 = 786432; b0 = bid - 1008; nb = 352; ssout = ss + 0;
  } else {
    in = qw; out = qw_bf; n8 = 393216; b0 = bid - 1360; nb = 176; ssout = ss + 1;
  }
  float s = 0.f;
  for (int i = b0 * 256 + tid; i < n8; i += nb * 256) {
    float4 a = ((const float4*)in)[2 * i];
    float4 b = ((const float4*)in)[2 * i + 1];
    if (ssout) {
      s += a.x * a.x + a.y * a.y + a.z * a.z + a.w * a.w;
      s += b.x * b.x + b.y * b.y + b.z * b.z + b.w * b.w;
    }
    uint4 o;
    o.x = f2bf(a.x) | ((unsigned)f2bf(a.y) << 16);
    o.y = f2bf(a.z) | ((unsigned)f2bf(a.w) << 16);
    o.z = f2bf(b.x) | ((unsigned)f2bf(b.y) << 16);
    o.w = f2bf(b.z) | ((unsigned)f2bf(b.w) << 16);
    ((uint4*)out)[i] = o;
  }
  if (ssout) {
    for (int off = 32; off; off >>= 1) s += __shfl_down(s, off);
    if ((tid & 63) == 0) red[tid >> 6] = s;
    __syncthreads();
    if (tid == 0) atomicAdd(ssout, red[0] + red[1] + red[2] + red[3]);
  }
}

// ======== merged GEMM: 128x192 tile, 4 waves, rotation, 2 blocks/CU, unroll-2 ========
// CACHE-TIER REMAP (R9): XCD x owns a 2-D panel — GEMM1: bm in [ (x>>2)*32, +32 ),
// bn in [ (x&3)*4, +4 ). Per-XCD B working set = 4 bn-tiles = 3.1 MB -> L2-RESIDENT
// for the whole kernel; active A set = 16bm x 4bn (first 64 local ids) -> A rows
// co-streamed by the 4 bn-blocks via L2, A total 32MB stays L3-resident.
// Kills the 786 MB/134us (~5.9 TB/s) B re-read stream that sat at the LLC ceiling.
// Schedule unchanged from R8 (queue-sim verified waits).
__global__ __launch_bounds__(256, 2) void k_gemm_cmb(
    const unsigned short* __restrict__ A1, const unsigned short* __restrict__ B1,
    const float* __restrict__ bias1, const float* __restrict__ g1,
    const float* __restrict__ ss1, unsigned short* __restrict__ C1,
    const unsigned short* __restrict__ A2, const unsigned short* __restrict__ B2,
    const float* __restrict__ bias2, const float* __restrict__ g2,
    const float* __restrict__ ss2, unsigned short* __restrict__ C2) {
  __shared__ __align__(16) unsigned short lA[2 * 128 * 64];  // 32 KB
  __shared__ __align__(16) unsigned short lB[2 * 192 * 64];  // 48 KB
  const int tid = threadIdx.x;
  const int wid = tid >> 6, lane = tid & 63;
  const int l15 = lane & 15, l4 = lane >> 4;
  const int wm = wid >> 1, wn = wid & 1;  // 2M x 2N waves
  const int rr8 = tid >> 3;
  const int scol8 = ((tid & 7) ^ (rr8 & 7)) << 3;  // pre-swizzled source col (rule 21)

  const unsigned short* A;
  const unsigned short* B;
  const float* bias;
  const float* gptr;
  const float* ssptr;
  unsigned short* C;
  int K, nt, bm, bn;
  if (blockIdx.x < 1024) {
    const int x = blockIdx.x & 7;      // XCD
    const int idx = blockIdx.x >> 3;   // [0,128) local
    const int bmHalf = idx >> 6;       // {0,1}
    const int rem = idx & 63;
    const int bn_l = rem >> 4;                  // [0,4)
    const int bm_l = bmHalf * 16 + (rem & 15);  // [0,32)
    bm = (x >> 2) * 32 + bm_l;         // [0,64)
    bn = (x & 3) * 4 + bn_l;           // [0,16)
    A = A1; B = B1; bias = bias1; gptr = g1; ssptr = ss1; C = C1;
    K = 2048; nt = 32;
  } else {
    const int bid = blockIdx.x - 1024;
    const int x = blockIdx.x & 7;      // == bid&7 (1024%8==0)
    const int idx = bid >> 3;          // [0,32)
    const int bm_l = idx & 7, bn_l = idx >> 3;  // [0,8),[0,4)
    bm = (x >> 2) * 8 + bm_l;          // [0,16)
    bn = (x & 3) * 4 + bn_l;           // [0,16)
    A = A2; B = B2; bias = bias2; gptr = g2; ssptr = ss2; C = C2;
    K = 1024; nt = 16;
  }

  const unsigned short* Ab = A + (size_t)bm * 128 * K;
  const unsigned short* Bb = B + (size_t)bn * 192 * K;

  // hoisted per-lane staging source pointers (unit U, half j)
  const unsigned short* sA00 = Ab + (size_t)(rr8) * K + scol8;
  const unsigned short* sA01 = Ab + (size_t)(32 + rr8) * K + scol8;
  const unsigned short* sA10 = Ab + (size_t)(64 + rr8) * K + scol8;
  const unsigned short* sA11 = Ab + (size_t)(96 + rr8) * K + scol8;
  const unsigned short* sB00 = Bb + (size_t)(rr8) * K + scol8;
  const unsigned short* sB01 = Bb + (size_t)(32 + rr8) * K + scol8;
  const unsigned short* sB10 = Bb + (size_t)(64 + rr8) * K + scol8;
  const unsigned short* sB11 = Bb + (size_t)(96 + rr8) * K + scol8;
  const unsigned short* sB20 = Bb + (size_t)(128 + rr8) * K + scol8;
  const unsigned short* sB21 = Bb + (size_t)(160 + rr8) * K + scol8;

#define SB() __builtin_amdgcn_sched_barrier(0);

#define STAGE_A(U, TS, BUFI)                                                       \
  {                                                                                \
    int ts_ = (TS) < nt ? (TS) : nt - 1;                                           \
    __builtin_amdgcn_global_load_lds(                                              \
        (gas_u32*)(sA##U##0 + (size_t)ts_ * 64),                                   \
        (las_u32*)(lA + (BUFI)*8192 + (U)*4096 + tid * 8), 16, 0, 0);              \
    __builtin_amdgcn_global_load_lds(                                              \
        (gas_u32*)(sA##U##1 + (size_t)ts_ * 64),                                   \
        (las_u32*)(lA + (BUFI)*8192 + (U)*4096 + 2048 + tid * 8), 16, 0, 0);       \
  }

#define STAGE_B(U, TS, BUFI)                                                       \
  {                                                                                \
    int ts_ = (TS) < nt ? (TS) : nt - 1;                                           \
    __builtin_amdgcn_global_load_lds(                                              \
        (gas_u32*)(sB##U##0 + (size_t)ts_ * 64),                                   \
        (las_u32*)(lB + (BUFI)*12288 + (U)*4096 + tid * 8), 16, 0, 0);             \
    __builtin_amdgcn_global_load_lds(                                              \
        (gas_u32*)(sB##U##1 + (size_t)ts_ * 64),                                   \
        (las_u32*)(lB + (BUFI)*12288 + (U)*4096 + 2048 + tid * 8), 16, 0, 0);      \
  }

#define LDSA(DST, MQ, TP)                                                          \
  _Pragma("unroll") for (int i2 = 0; i2 < 2; ++i2) {                               \
    int rl = wm * 64 + ((MQ)*2 + i2) * 16 + l15;                                   \
    const unsigned short* ap = lA + (TP)*8192 + rl * 64;                           \
    int s8 = rl & 7;                                                               \
    DST[i2][0] = *(const bf16x8*)(ap + ((l4 ^ s8) << 3));                          \
    DST[i2][1] = *(const bf16x8*)(ap + (((4 | l4) ^ s8) << 3));                    \
  }

#define LDSB(DST, NQ, TP)                                                          \
  _Pragma("unroll") for (int j3 = 0; j3 < 3; ++j3) {                               \
    int rl = wn * 96 + ((NQ)*3 + j3) * 16 + l15;                                   \
    const unsigned short* bp = lB + (TP)*12288 + rl * 64;                          \
    int s8 = rl & 7;                                                               \
    DST[j3][0] = *(const bf16x8*)(bp + ((l4 ^ s8) << 3));                          \
    DST[j3][1] = *(const bf16x8*)(bp + (((4 | l4) ^ s8) << 3));                    \
  }

#define MFMA12(MQ, NQ, AF, BF)                                                     \
  _Pragma("unroll") for (int ks = 0; ks < 2; ++ks)                                 \
  _Pragma("unroll") for (int i2 = 0; i2 < 2; ++i2)                                 \
  _Pragma("unroll") for (int j3 = 0; j3 < 3; ++j3)                                 \
    acc[(MQ)*2 + i2][(NQ)*3 + j3] = __builtin_amdgcn_mfma_f32_16x16x32_bf16(       \
        AF[i2][ks], BF[j3][ks], acc[(MQ)*2 + i2][(NQ)*3 + j3], 0, 0, 0);

// one K-tile, all indices literal: CP = buffer of tile t, NP = other buffer
#define TILE_BODY(T, CP, NP)                                                       \
  LDSB(b1_, 1, CP)                                                                 \
  STAGE_B(2, (T) + 1, NP)                                                          \
  __builtin_amdgcn_s_setprio(1);                                                   \
  MFMA12(0, 0, a0_, b0_)                                                           \
  __builtin_amdgcn_s_setprio(0);                                                   \
  LDSA(a1_, 1, CP)                                                                 \
  __builtin_amdgcn_s_setprio(1);                                                   \
  MFMA12(0, 1, a0_, b1_)                                                           \
  __builtin_amdgcn_s_setprio(0);                                                   \
  asm volatile("s_waitcnt lgkmcnt(0)" ::: "memory");                               \
  asm volatile("s_waitcnt vmcnt(6)" ::: "memory");                                 \
  SB()                                                                             \
  __builtin_amdgcn_s_barrier();                                                    \
  LDSA(a0_, 0, NP)                                                                 \
  STAGE_A(0, (T) + 2, CP) STAGE_A(1, (T) + 2, CP)                                  \
  __builtin_amdgcn_s_setprio(1);                                                   \
  MFMA12(1, 0, a1_, b0_)                                                           \
  __builtin_amdgcn_s_setprio(0);                                                   \
  asm volatile("s_waitcnt vmcnt(4)" ::: "memory");                                 \
  SB()                                                                             \
  __builtin_amdgcn_s_barrier();                                                    \
  LDSB(b0_, 0, NP)                                                                 \
  STAGE_B(0, (T) + 2, CP) STAGE_B(1, (T) + 2, CP)                                  \
  __builtin_amdgcn_s_setprio(1);                                                   \
  MFMA12(1, 1, a1_, b1_)                                                           \
  __builtin_amdgcn_s_setprio(0);

  f32x4 acc[4][6] = {};
  bf16x8 a0_[2][2], a1_[2][2], b0_[3][2], b1_[3][2];

  // ---- prologue: tile0 (10 loads) + A(1) (4); wait tile0; B01(1) post-barrier ----
  STAGE_A(0, 0, 0) STAGE_A(1, 0, 0) STAGE_B(0, 0, 0) STAGE_B(1, 0, 0) STAGE_B(2, 0, 0)
  STAGE_A(0, 1, 1) STAGE_A(1, 1, 1)
  asm volatile("s_waitcnt vmcnt(4)" ::: "memory");
  SB()
  __builtin_amdgcn_s_barrier();
  LDSA(a0_, 0, 0)
  STAGE_B(0, 1, 1) STAGE_B(1, 1, 1)
  LDSB(b0_, 0, 0)

  for (int t = 0; t < nt; t += 2) {
    TILE_BODY(t, 0, 1)      // even tile: cp=0, np=1
    TILE_BODY(t + 1, 1, 0)  // odd tile:  cp=1, np=0
  }

  asm volatile("s_waitcnt vmcnt(0)" ::: "memory");

  const int N = 3072;
  float s = gptr[0] / sqrtf(ssptr[0]);
#pragma unroll
  for (int nj = 0; nj < 6; ++nj) {
    int gcol = bn * 192 + wn * 96 + nj * 16 + l15;
    float bv = bias[gcol];
#pragma unroll
    for (int mi = 0; mi < 4; ++mi) {
#pragma unroll
      for (int r = 0; r < 4; ++r) {
        int grow = bm * 128 + wm * 64 + mi * 16 + l4 * 4 + r;
        float v = fmaxf(acc[mi][nj][r] * s + bv, 0.f);
        C[(size_t)grow * N + gcol] = f2bf(v);
      }
    }
  }
#undef STAGE_A
#undef STAGE_B
#undef LDSA
#undef LDSB
#undef MFMA12
#undef TILE_BODY
#undef SB
}

// -------- glimpse v5b: b-MAJOR block ids (4 blocks sharing V[b] -> same XCD L2) --------
// block id = b*4 + hv; hv = {h4, vh}. 64 V-rows x 4 heads per block, XOR-swizzled LDS.
__global__ __launch_bounds__(256, 2) void k_glimpse5(
    const unsigned short* __restrict__ Vh, const unsigned short* __restrict__ Qh,
    const float* __restrict__ hmat, const float* __restrict__ hbias,
    float* __restrict__ out) {
  __shared__ __align__(16) unsigned short lV[3][64 * 64];    // 24 KB
  __shared__ __align__(16) unsigned short lQ[2][4][32 * 64]; // 32 KB
  int tid = threadIdx.x;
  int wid = tid >> 6, lane = tid & 63;
  int l15 = lane & 15, l4 = lane >> 4;

  int id = blockIdx.x;
  int b = id >> 2, hv = id & 3;
  int h4 = hv & 1, vh = hv >> 1;  // heads h4*4..+3, V rows vh*64..+63

  const unsigned short* Vb = Vh + (size_t)b * 128 * 3072 + (size_t)vh * 64 * 3072;
  const unsigned short* Qb = Qh + (size_t)b * 32 * 3072;
  const float* hr0 = hmat + (h4 * 4 + 0) * 3072;
  const float* hr1 = hmat + (h4 * 4 + 1) * 3072;
  const float* hr2 = hmat + (h4 * 4 + 2) * 3072;
  const float* hr3 = hmat + (h4 * 4 + 3) * 3072;

  f32x4 acc[4][2] = {};
  const int rr8 = tid >> 3;
  const int ch8 = tid & 7;
  const int scol8 = (ch8 ^ (rr8 & 7)) << 3;
  const int qwoff = rr8 * 64 + scol8;
  const int qc = ch8 * 8;
  const int NT = 48;

#define VSTAGE(T, SLOT)                                                          \
  {                                                                              \
    int tc = (T) < NT ? (T) : NT - 1;                                            \
    _Pragma("unroll") for (int j = 0; j < 2; ++j) {                              \
      __builtin_amdgcn_global_load_lds(                                          \
          (gas_u32*)(Vb + (size_t)(j * 32 + rr8) * 3072 + tc * 64 + scol8),      \
          (las_u32*)(&lV[SLOT][0] + j * 2048 + tid * 8), 16, 0, 0);              \
    }                                                                            \
  }

#define QLOAD(T, RQ, H)                                                          \
  {                                                                              \
    int tc = (T) < NT ? (T) : NT - 1;                                            \
    RQ = *(const uint4*)(Qb + (size_t)rr8 * 3072 + tc * 64 + qc);                \
    H[0] = ((const float4*)(hr0 + tc * 64 + qc))[0];                             \
    H[1] = ((const float4*)(hr0 + tc * 64 + qc))[1];                             \
    H[2] = ((const float4*)(hr1 + tc * 64 + qc))[0];                             \
    H[3] = ((const float4*)(hr1 + tc * 64 + qc))[1];                             \
    H[4] = ((const float4*)(hr2 + tc * 64 + qc))[0];                             \
    H[5] = ((const float4*)(hr2 + tc * 64 + qc))[1];                             \
    H[6] = ((const float4*)(hr3 + tc * 64 + qc))[0];                             \
    H[7] = ((const float4*)(hr3 + tc * 64 + qc))[1];                             \
  }

#define QWRITE(CB, RQ, H)                                                        \
  {                                                                              \
    float e0 = bf2f((unsigned short)(RQ.x & 0xffff));                            \
    float e1 = bf2f((unsigned short)(RQ.x >> 16));                               \
    float e2 = bf2f((unsigned short)(RQ.y & 0xffff));                            \
    float e3 = bf2f((unsigned short)(RQ.y >> 16));                               \
    float e4 = bf2f((unsigned short)(RQ.z & 0xffff));                            \
    float e5 = bf2f((unsigned short)(RQ.z >> 16));                               \
    float e6 = bf2f((unsigned short)(RQ.w & 0xffff));                            \
    float e7 = bf2f((unsigned short)(RQ.w >> 16));                               \
    _Pragma("unroll") for (int hh = 0; hh < 4; ++hh) {                           \
      uint4 o;                                                                   \
      o.x = f2bf(e0 * H[hh * 2].x) | ((unsigned)f2bf(e1 * H[hh * 2].y) << 16);   \
      o.y = f2bf(e2 * H[hh * 2].z) | ((unsigned)f2bf(e3 * H[hh * 2].w) << 16);   \
      o.z = f2bf(e4 * H[hh * 2 + 1].x) |                                         \
            ((unsigned)f2bf(e5 * H[hh * 2 + 1].y) << 16);                        \
      o.w = f2bf(e6 * H[hh * 2 + 1].z) |                                         \
            ((unsigned)f2bf(e7 * H[hh * 2 + 1].w) << 16);                        \
      *(uint4*)(&lQ[CB][hh][0] + qwoff) = o;                                     \
    }                                                                            \
  }

#define GMFMA(SLOT, CB)                                                          \
  {                                                                              \
    int rlv = wid * 16 + l15;                                                    \
    int s8v = rlv & 7;                                                           \
    bf16x8 af[2];                                                                \
    af[0] = *(const bf16x8*)(&lV[SLOT][0] + rlv * 64 + ((l4 ^ s8v) << 3));       \
    af[1] = *(const bf16x8*)(&lV[SLOT][0] + rlv * 64 + (((4 | l4) ^ s8v) << 3)); \
    _Pragma("unroll") for (int hh = 0; hh < 4; ++hh) {                           \
      _Pragma("unroll") for (int nj = 0; nj < 2; ++nj) {                         \
        int rlq = nj * 16 + l15;                                                 \
        int s8q = rlq & 7;                                                       \
        bf16x8 bq0 = *(const bf16x8*)(&lQ[CB][hh][0] + rlq * 64 +                \
                                      ((l4 ^ s8q) << 3));                        \
        bf16x8 bq1 = *(const bf16x8*)(&lQ[CB][hh][0] + rlq * 64 +                \
                                      (((4 | l4) ^ s8q) << 3));                  \
        acc[hh][nj] =                                                            \
            __builtin_amdgcn_mfma_f32_16x16x32_bf16(af[0], bq0, acc[hh][nj], 0, 0, 0); \
        acc[hh][nj] =                                                            \
            __builtin_amdgcn_mfma_f32_16x16x32_bf16(af[1], bq1, acc[hh][nj], 0, 0, 0); \
      }                                                                          \
    }                                                                            \
  }

#define GBODY(T, CQ, CH, NQ, NH)                                                 \
  {                                                                              \
    QLOAD((T) + 2, NQ, NH)                                                       \
    asm volatile("s_waitcnt vmcnt(11)" ::: "memory");                            \
    asm volatile("s_waitcnt lgkmcnt(0)" ::: "memory");                           \
    __builtin_amdgcn_sched_barrier(0);                                           \
    __builtin_amdgcn_s_barrier();                                                \
    VSTAGE((T) + 2, ((T) + 2) % 3)                                               \
    QWRITE(((T) + 1) & 1, CQ, CH)                                                \
    GMFMA((T) % 3, (T) & 1)                                                      \
  }

  uint4 aq, bq_;
  float4 ah[8], bh[8];

  QLOAD(0, aq, ah)
  QLOAD(1, bq_, bh)
  VSTAGE(0, 0)
  VSTAGE(1, 1)
  asm volatile("s_waitcnt vmcnt(13)" ::: "memory");
  __builtin_amdgcn_sched_barrier(0);
  QWRITE(0, aq, ah)

  for (int t = 0; t < NT; t += 2) {
    GBODY(t, bq_, bh, aq, ah)
    GBODY(t + 1, aq, ah, bq_, bh)
  }
  asm volatile("s_waitcnt vmcnt(0) lgkmcnt(0)" ::: "memory");

#pragma unroll
  for (int hh = 0; hh < 4; ++hh) {
    int h = h4 * 4 + hh;
    float hb = hbias[h];
    float* ob = out + (size_t)(b * 8 + h) * 128 * 32;
#pragma unroll
    for (int nj = 0; nj < 2; ++nj)
#pragma unroll
      for (int r = 0; r < 4; ++r) {
        int row = vh * 64 + wid * 16 + l4 * 4 + r;
        int col = nj * 16 + l15;
        ob[row * 32 + col] = acc[hh][nj][r] + hb;
      }
  }
#undef VSTAGE
#undef QLOAD
#undef QWRITE
#undef GMFMA
#undef GBODY
}

extern "C" void kernel_launch(void* const* d_in, const int* in_sizes, int n_in,
                              void* d_out, int out_size, void* d_ws, size_t ws_size,
                              hipStream_t stream) {
  const float* v = (const float*)d_in[0];
  const float* q = (const float*)d_in[1];
  const float* v_w = (const float*)d_in[2];
  const float* v_g = (const float*)d_in[3];
  const float* v_b = (const float*)d_in[4];
  const float* q_w = (const float*)d_in[5];
  const float* q_g = (const float*)d_in[6];
  const float* q_b = (const float*)d_in[7];
  const float* hmat = (const float*)d_in[8];
  const float* hbias = (const float*)d_in[9];
  float* out = (float*)d_out;

  const size_t n_v = 16777216;   // 64*128*2048
  const size_t n_vw = 6291456;   // 3072*2048
  const size_t n_q = 2097152;    // 64*32*1024
  const size_t n_qw = 3145728;   // 3072*1024
  const size_t n_vh = 25165824;  // 8192*3072
  const size_t n_qh = 6291456;   // 2048*3072

  char* ws = (char*)d_ws;
  float* ss = (float*)ws;
  size_t off = 256;
  unsigned short* v_bf = (unsigned short*)(ws + off);  off += n_v * 2;
  unsigned short* vw_bf = (unsigned short*)(ws + off); off += n_vw * 2;
  unsigned short* q_bf = (unsigned short*)(ws + off);  off += n_q * 2;
  unsigned short* qw_bf = (unsigned short*)(ws + off); off += n_qw * 2;
  unsigned short* v_h = (unsigned short*)(ws + off);   off += n_vh * 2;
  unsigned short* q_h = (unsigned short*)(ws + off);   off += n_qh * 2;

  (void)hipMemsetAsync(ss, 0, 8, stream);
  k_prep<<<1536, 256, 0, stream>>>(v, q, v_w, q_w, v_bf, q_bf, vw_bf, qw_bf, ss);

  // merged GEMM1 (1024 blocks) + GEMM2 (256 blocks), cache-tier XCD remap
  k_gemm_cmb<<<1280, 256, 0, stream>>>(v_bf, vw_bf, v_b, v_g, ss + 0, v_h,
                                       q_bf, qw_bf, q_b, q_g, ss + 1, q_h);

  k_glimpse5<<<256, 256, 0, stream>>>(v_h, q_h, hmat, hbias, out);
}